// Round 5
// baseline (135.376 us; speedup 1.0000x reference)
//
#include <hip/hip_runtime.h>

typedef __attribute__((ext_vector_type(8))) short bf16x8;
typedef __attribute__((ext_vector_type(8))) _Float16 f16x8;
typedef __attribute__((ext_vector_type(4))) float f32x4;
typedef __attribute__((ext_vector_type(4))) _Float16 f16x4;
typedef __attribute__((ext_vector_type(2))) _Float16 f16x2;

#define NPTS   40000
#define MOUT   40000
#define EDG    500000
#define FIN    32
#define COUT   64
#define KP     15
#define KFDIM  (KP * FIN)          // 480
#define EXTENT 0.6f

// Block agg tile: 16 segments x 488 f16 (976B rows = 61*16B, conflict-free b128)
#define ASTR 488

#define FEAT_BLKS  (NPTS * FIN / 1024)            // 1250
#define PTS_BLKS   ((NPTS + 255) / 256)           // 157
#define OP_BLKS    ((MOUT + 255) / 256)           // 157
#define ROW_BLKS   ((EDG + 255) / 256)            // 1954
#define WT_BLKS    (KFDIM * COUT / 256)           // 120
#define PRE_BLKS   (FEAT_BLKS + PTS_BLKS + OP_BLKS + ROW_BLKS + WT_BLKS)

__device__ __forceinline__ short f2bf(float x) {
    union { float f; unsigned u; } v; v.f = x;
    unsigned r = (v.u + 0x7fffu + ((v.u >> 16) & 1u)) >> 16;
    return (short)r;
}

// ============================================================================
// Preprocess (ONE launch, branch by block range) — unchanged.
// ============================================================================
__global__ __launch_bounds__(256) void preprocess_all(
    const float* __restrict__ features, _Float16* __restrict__ feat_i,
    const float* __restrict__ pts, float4* __restrict__ p4,
    const float* __restrict__ opts, float4* __restrict__ op4,
    const int* __restrict__ seg_ids, int* __restrict__ row_start,
    const float* __restrict__ k_values, _Float16* __restrict__ w_t)
{
    const int bid = blockIdx.x;
    if (bid < FEAT_BLKS) {
        const int d0 = (bid * 256 + threadIdx.x) * 4;
        #pragma unroll
        for (int u = 0; u < 4; ++u) {
            const int d = d0 + u;
            const int p = d >> 5, q = d & 31;
            const int fp = q >> 1, h = q & 1;
            feat_i[d] = (_Float16)features[p * FIN + fp + 16 * h];
        }
    } else if (bid < FEAT_BLKS + PTS_BLKS) {
        const int i = (bid - FEAT_BLKS) * 256 + threadIdx.x;
        if (i < NPTS) {
            const float* p = pts + 3 * i;
            p4[i] = make_float4(p[0], p[1], p[2], 0.f);
        }
    } else if (bid < FEAT_BLKS + PTS_BLKS + OP_BLKS) {
        const int i = (bid - FEAT_BLKS - PTS_BLKS) * 256 + threadIdx.x;
        if (i < MOUT) {
            const float* p = opts + 3 * i;
            op4[i] = make_float4(p[0], p[1], p[2], 0.f);
        }
    } else if (bid < FEAT_BLKS + PTS_BLKS + OP_BLKS + ROW_BLKS) {
        const int e = (bid - FEAT_BLKS - PTS_BLKS - OP_BLKS) * 256 + threadIdx.x;
        if (e >= EDG) return;
        const int cur  = seg_ids[e];
        const int prev = (e == 0) ? -1 : seg_ids[e - 1];
        for (int m = prev + 1; m <= cur; ++m) row_start[m] = e;
        if (e == EDG - 1)
            for (int m = cur + 1; m <= MOUT; ++m) row_start[m] = EDG;
    } else {
        const int d = (bid - FEAT_BLKS - PTS_BLKS - OP_BLKS - ROW_BLKS) * 256
                      + threadIdx.x;                 // 0 .. 30719
        const int c = d / KFDIM, r = d % KFDIM;
        const int k = r >> 5, q = r & 31;
        const int fp = q >> 1, h = q & 1;
        w_t[d] = (_Float16)k_values[(k * FIN + fp + 16 * h) * COUT + c];
    }
}

// ============================================================================
// Fused kernel: block = 16 segments.
// Phase 1 R18: flattened STEP STREAM + 2-bank pipeline + windowed points.
//  - R17 regression diagnosis: 8 gathers/step + thin consume left ~200cy of
//    VMEM latency exposed. Fix BOTH arms:
//  - points: gathered ONCE per 64-edge window slide (points4[nbrreg] -> 3
//    regs p_win); per-step coords via 12 __shfl (LDS pipe, no VMEM).
//  - feat: 4 dword gathers/step (B-fragment direct, no LDS transpose),
//    prefetched ~1.5 steps ahead via a 2-bank pipeline over the FLATTENED
//    per-wave step stream (segment advance = select-chains over precomputed
//    next-nonempty triples; no runtime-indexed arrays -> no scratch).
//  - acc flushes to aggT on segment change; empty rows pre-zeroed.
// Arithmetic source-identical to R16/R17 -> bit-identical output.
// (256,4): est ~110 VGPR (2 banks + acc + o-preloads). 1 block x 15.6KB LDS.
// Tripwire: >=102us or absmax change -> revert to R16.
// ============================================================================
__global__ __launch_bounds__(256, 4) void kpconv_fused2(
    const float4* __restrict__ points4,
    const _Float16* __restrict__ feat_i,
    const float4* __restrict__ op4,
    const int*   __restrict__ nbr_idx,
    const int*   __restrict__ row_start,
    const float* __restrict__ k_points,
    const _Float16* __restrict__ w_t,
    float* __restrict__ out)
{
    __shared__ __align__(16) _Float16 aggT[16 * ASTR];          // 15616 B

    const int tid  = threadIdx.x;
    const int wave = tid >> 6;
    const int lane = tid & 63;
    const int quad = lane >> 4;
    const int l16  = lane & 15;
    const int m0   = blockIdx.x * 16;

    // ---- pre-zero this wave's 4 aggT rows (4*976B = 244 x 16B chunks) ----
    {
        char* z = (char*)(aggT + wave * 4 * ASTR);
        #pragma unroll
        for (int i = 0; i < 4; ++i) {
            const int c = i * 64 + lane;
            if (c < 244) *(uint4*)(z + c * 16) = make_uint4(0, 0, 0, 0);
        }
    }

    // per-lane kernel point (A-fragment row = l16)
    const int  myk = l16 < KP ? l16 : 0;
    const float kxx = k_points[myk * 3 + 0];
    const float kyy = k_points[myk * 3 + 1];
    const float kzz = k_points[myk * 3 + 2];
    const bool  vk  = (l16 < KP);
    const float inv_ext = 1.f / EXTENT;

    // ---- segment bounds (wave-uniform) ----
    int rs[5];
    #pragma unroll
    for (int i = 0; i < 5; ++i) rs[i] = row_start[m0 + wave * 4 + i];

    // o preloads (xyz) for the 4 segments — named, selected by cur_j later
    const float4 o0 = op4[m0 + wave * 4 + 0];
    const float4 o1 = op4[m0 + wave * 4 + 1];
    const float4 o2 = op4[m0 + wave * 4 + 2];
    const float4 o3 = op4[m0 + wave * 4 + 3];

    // ---- next-nonempty-segment triples (es,e1,j); sentinel=(rs4,rs4,4) ----
    int n3es = rs[4], n3e1 = rs[4], n3j = 4;
    int n2es, n2e1, n2j;
    if (rs[3] < rs[4]) { n2es = rs[3]; n2e1 = rs[4]; n2j = 3; }
    else               { n2es = n3es;  n2e1 = n3e1;  n2j = n3j; }
    int n1es, n1e1, n1j;
    if (rs[2] < rs[3]) { n1es = rs[2]; n1e1 = rs[3]; n1j = 2; }
    else               { n1es = n2es;  n1e1 = n2e1;  n1j = n2j; }
    int n0es, n0e1, n0j;
    if (rs[1] < rs[2]) { n0es = rs[1]; n0e1 = rs[2]; n0j = 1; }
    else               { n0es = n1es;  n0e1 = n1e1;  n0j = n1j; }

    int esA, e1A, jA;
    if (rs[0] < rs[1]) { esA = rs[0]; e1A = rs[1]; jA = 0; }
    else               { esA = n0es;  e1A = n0e1;  jA = n0j; }

    auto adv = [&](int es, int e1, int j, int& res, int& re1, int& rj) {
        const int nes_ = (j == 0) ? n0es : (j == 1) ? n1es : (j == 2) ? n2es : n3es;
        const int ne1_ = (j == 0) ? n0e1 : (j == 1) ? n1e1 : (j == 2) ? n2e1 : n3e1;
        const int nj_  = (j == 0) ? n0j  : (j == 1) ? n1j  : (j == 2) ? n2j  : n3j;
        const bool more = (es + 16 < e1);
        res = more ? es + 16 : nes_;
        re1 = more ? e1 : ne1_;
        rj  = more ? j : nj_;
    };

    // ---- window + 2-bank pipeline state ----
    int wb = -0x40000000;
    int nbrreg = 0;
    float pwx = 0.f, pwy = 0.f, pwz = 0.f;   // window point coords (edge wb+lane)
    float pxb[2][4], pyb[2][4], pzb[2][4];   // bank regs (static indices only)
    unsigned ftb[2][4];

#define PREF(B, ES)                                                           \
    {                                                                         \
        const int es_ = (ES);                                                 \
        if (es_ + 15 > wb + 63) {                                             \
            wb = es_;                                                         \
            const int a_  = wb + lane;                                        \
            const int ac_ = a_ < EDG ? a_ : EDG - 1;                          \
            nbrreg = nbr_idx[ac_];                                            \
            const float4 pw_ = points4[nbrreg];                               \
            pwx = pw_.x; pwy = pw_.y; pwz = pw_.z;                            \
        }                                                                     \
        const int base_ = es_ - wb + quad * 4;                                \
        _Pragma("unroll")                                                     \
        for (int jj = 0; jj < 4; ++jj) {                                      \
            const int nb_ = __shfl(nbrreg, base_ + jj);                       \
            ftb[B][jj] = *(const unsigned*)(feat_i + nb_ * FIN + 2 * l16);    \
            pxb[B][jj] = __shfl(pwx, base_ + jj);                             \
            pyb[B][jj] = __shfl(pwy, base_ + jj);                             \
            pzb[B][jj] = __shfl(pwz, base_ + jj);                             \
        }                                                                     \
    }

#define FLUSH()                                                               \
    if (cur_j >= 0) {                                                         \
        _Float16* dst_ = aggT + (wave * 4 + cur_j) * ASTR;                    \
        _Pragma("unroll")                                                     \
        for (int r = 0; r < 4; ++r) {                                         \
            const int krow_ = quad * 4 + r;                                   \
            if (krow_ < KP) {                                                 \
                f16x2 v_ = {(_Float16)c_lo[r], (_Float16)c_hi[r]};            \
                *(f16x2*)(dst_ + krow_ * 32 + 2 * l16) = v_;                  \
            }                                                                 \
        }                                                                     \
        c_lo = (f32x4){0.f, 0.f, 0.f, 0.f};                                   \
        c_hi = (f32x4){0.f, 0.f, 0.f, 0.f};                                   \
    }

#define SELECT_O()                                                            \
    {                                                                         \
        ox = cur_j == 0 ? o0.x : cur_j == 1 ? o1.x : cur_j == 2 ? o2.x : o3.x;\
        oy = cur_j == 0 ? o0.y : cur_j == 1 ? o1.y : cur_j == 2 ? o2.y : o3.y;\
        oz = cur_j == 0 ? o0.z : cur_j == 1 ? o1.z : cur_j == 2 ? o2.z : o3.z;\
    }

#define CONSUME(B, ES, E1, J)                                                 \
    {                                                                         \
        if ((J) != cur_j) { FLUSH(); cur_j = (J); SELECT_O(); }               \
        f16x4 af;                                                             \
        _Pragma("unroll")                                                     \
        for (int jj = 0; jj < 4; ++jj) {                                      \
            const float rx_ = pxb[B][jj] - ox;                                \
            const float ry_ = pyb[B][jj] - oy;                                \
            const float rz_ = pzb[B][jj] - oz;                                \
            const float dx_ = rx_ - kxx, dy_ = ry_ - kyy, dz_ = rz_ - kzz;    \
            float w_ = 1.f - sqrtf(dx_*dx_ + dy_*dy_ + dz_*dz_) * inv_ext;    \
            w_ = w_ > 0.f ? w_ : 0.f;                                         \
            if (!vk || ((ES) + quad * 4 + jj) >= (E1)) w_ = 0.f;              \
            af[jj] = (_Float16)w_;                                            \
        }                                                                     \
        union { unsigned u; f16x2 h; } u0_, u1_, u2_, u3_;                    \
        u0_.u = ftb[B][0]; u1_.u = ftb[B][1];                                 \
        u2_.u = ftb[B][2]; u3_.u = ftb[B][3];                                 \
        const f16x4 blo_ = {u0_.h[0], u1_.h[0], u2_.h[0], u3_.h[0]};          \
        const f16x4 bhi_ = {u0_.h[1], u1_.h[1], u2_.h[1], u3_.h[1]};          \
        c_lo = __builtin_amdgcn_mfma_f32_16x16x16f16(af, blo_, c_lo, 0, 0, 0);\
        c_hi = __builtin_amdgcn_mfma_f32_16x16x16f16(af, bhi_, c_hi, 0, 0, 0);\
    }

    int cur_j = -1;
    float ox = 0.f, oy = 0.f, oz = 0.f;
    f32x4 c_lo = {0.f, 0.f, 0.f, 0.f};
    f32x4 c_hi = {0.f, 0.f, 0.f, 0.f};

    int esB, e1B, jB;
    adv(esA, e1A, jA, esB, e1B, jB);
    PREF(0, esA)
    PREF(1, esB)

    for (;;) {
        if (esA >= e1A) break;
        int esC, e1C, jC;
        adv(esB, e1B, jB, esC, e1C, jC);
        CONSUME(0, esA, e1A, jA)
        PREF(0, esC)
        if (esB >= e1B) break;
        int esD, e1D, jD;
        adv(esC, e1C, jC, esD, e1D, jD);
        CONSUME(1, esB, e1B, jB)
        PREF(1, esD)
        esA = esC; e1A = e1C; jA = jC;
        esB = esD; e1B = e1D; jB = jD;
    }
    FLUSH()

#undef PREF
#undef FLUSH
#undef SELECT_O
#undef CONSUME

    __syncthreads();

    // ---- Phase 2: C[16 segs x 16 cols] per wave, B in-loop from w_t ----
    const int bcol = wave * 16 + l16;
    const _Float16* wrow = w_t + (size_t)bcol * KFDIM + quad * 8;
    const _Float16* arow = aggT + l16 * ASTR + quad * 8;

    f32x4 c = {0.f, 0.f, 0.f, 0.f};
    #pragma unroll
    for (int s = 0; s < 15; ++s) {
        const f16x8 a = *(const f16x8*)(arow + 32 * s);
        const f16x8 b = *(const f16x8*)(wrow + 32 * s);
        c = __builtin_amdgcn_mfma_f32_16x16x32_f16(a, b, c, 0, 0, 0);
    }

    // C/D: col = lane&15 (-> bcol), row = quad*4 + r (= local segment)
    #pragma unroll
    for (int r = 0; r < 4; ++r)
        out[(m0 + quad * 4 + r) * COUT + bcol] = c[r];
}

// ============================================================================
// Fallback (small ws, needs 38.4 MB): binary-search K=32 agg + plain gemm.
// ============================================================================
__global__ __launch_bounds__(256, 4) void kpconv_agg_fallback(
    const float* __restrict__ points,
    const float* __restrict__ features,
    const float* __restrict__ output_points,
    const int*   __restrict__ nbr_idx,
    const int*   __restrict__ seg_ids,
    const float* __restrict__ k_points,
    _Float16* __restrict__ agg_g)
{
    __shared__ int seg_start[5];

    const int tid = threadIdx.x;
    const int m0  = blockIdx.x * 4;

    if (tid <= 4) {
        const int target = m0 + tid;
        int lo = 0, hi = EDG;
        while (lo < hi) {
            int mid = (lo + hi) >> 1;
            if (seg_ids[mid] < target) lo = mid + 1; else hi = mid;
        }
        seg_start[tid] = lo;
    }
    __syncthreads();

    const int wave = tid >> 6;
    const int lane = tid & 63;
    const int quad = lane >> 4;
    const int l16  = lane & 15;

    const int m = m0 + wave;
    const float ox = output_points[m * 3 + 0];
    const float oy = output_points[m * 3 + 1];
    const float oz = output_points[m * 3 + 2];

    const int myk = l16 < KP ? l16 : 0;
    const float kpx = k_points[myk * 3 + 0];
    const float kpy = k_points[myk * 3 + 1];
    const float kpz = k_points[myk * 3 + 2];
    const float inv_ext = 1.f / EXTENT;

    const int e0 = seg_start[wave], e1 = seg_start[wave + 1];

    f32x4 c_lo = {0.f, 0.f, 0.f, 0.f};
    f32x4 c_hi = {0.f, 0.f, 0.f, 0.f};

    for (int es = e0; es < e1; es += 32) {
        const int last = e1 - 1;
        const int ebase = es + quad * 8;

        int nb[8];
        #pragma unroll
        for (int j = 0; j < 8; ++j) {
            const int e = ebase + j;
            nb[j] = nbr_idx[e < e1 ? e : last];
        }

        bf16x8 afrag, blo, bhi;
        #pragma unroll
        for (int j = 0; j < 8; ++j) {
            const float* pp = points + nb[j] * 3;
            const float rx = pp[0] - ox;
            const float ry = pp[1] - oy;
            const float rz = pp[2] - oz;
            const float dx = rx - kpx, dy = ry - kpy, dz = rz - kpz;
            const float d2 = dx * dx + dy * dy + dz * dz;
            float w = 1.f - sqrtf(d2) * inv_ext;
            w = w > 0.f ? w : 0.f;
            if (l16 >= KP || ebase + j >= e1) w = 0.f;
            afrag[j] = f2bf(w);
        }

        #pragma unroll
        for (int j = 0; j < 8; ++j) {
            const float* fp = features + nb[j] * FIN + l16;
            blo[j] = f2bf(fp[0]);
            bhi[j] = f2bf(fp[16]);
        }

        c_lo = __builtin_amdgcn_mfma_f32_16x16x32_bf16(afrag, blo, c_lo, 0, 0, 0);
        c_hi = __builtin_amdgcn_mfma_f32_16x16x32_bf16(afrag, bhi, c_hi, 0, 0, 0);
    }

    _Float16* dst = agg_g + (size_t)m * KFDIM;
    #pragma unroll
    for (int r = 0; r < 4; ++r) {
        const int krow = quad * 4 + r;
        if (krow < KP) {
            dst[krow * FIN + l16]      = (_Float16)c_lo[r];
            dst[krow * FIN + 16 + l16] = (_Float16)c_hi[r];
        }
    }
}

__global__ __launch_bounds__(256, 4) void kpconv_gemm_plain(
    const _Float16* __restrict__ agg_g,
    const float* __restrict__ k_values,
    float* __restrict__ out)
{
    const int tid  = threadIdx.x;
    const int wave = tid >> 6;
    const int lane = tid & 63;
    const int quad = lane >> 4;
    const int l16  = lane & 15;
    const int m0   = blockIdx.x * 32;
    const int bcol = wave * 16 + l16;

    f16x8 bfr[15];
    #pragma unroll
    for (int s = 0; s < 15; ++s) {
        #pragma unroll
        for (int j = 0; j < 8; ++j)
            bfr[s][j] = (_Float16)k_values[(32 * s + quad * 8 + j) * COUT + bcol];
    }

    const _Float16* arow0 = agg_g + (size_t)(m0 + l16) * KFDIM + quad * 8;
    const _Float16* arow1 = arow0 + 16 * KFDIM;

    f32x4 c0 = {0.f, 0.f, 0.f, 0.f};
    f32x4 c1 = {0.f, 0.f, 0.f, 0.f};
    #pragma unroll
    for (int s = 0; s < 15; ++s) {
        const f16x8 a0 = *(const f16x8*)(arow0 + 32 * s);
        const f16x8 a1 = *(const f16x8*)(arow1 + 32 * s);
        c0 = __builtin_amdgcn_mfma_f32_16x16x32_f16(a0, bfr[s], c0, 0, 0, 0);
        c1 = __builtin_amdgcn_mfma_f32_16x16x32_f16(a1, bfr[s], c1, 0, 0, 0);
    }

    #pragma unroll
    for (int r = 0; r < 4; ++r) {
        out[(m0 + quad * 4 + r) * COUT + bcol]      = c0[r];
        out[(m0 + 16 + quad * 4 + r) * COUT + bcol] = c1[r];
    }
}

extern "C" void kernel_launch(void* const* d_in, const int* in_sizes, int n_in,
                              void* d_out, int out_size, void* d_ws, size_t ws_size,
                              hipStream_t stream) {
    const float* points        = (const float*)d_in[0];
    const float* features      = (const float*)d_in[1];
    const float* output_points = (const float*)d_in[2];
    const int*   nbr_idx       = (const int*)d_in[3];
    const int*   seg_ids       = (const int*)d_in[4];
    const float* k_points      = (const float*)d_in[5];
    const float* k_values      = (const float*)d_in[6];
    float* out = (float*)d_out;

    const size_t feat_bytes = (size_t)NPTS * FIN * sizeof(_Float16);           // 2.56 MB
    const size_t pts4_bytes = (size_t)NPTS * sizeof(float4);                   // 0.64 MB
    const size_t op4_bytes  = (size_t)MOUT * sizeof(float4);                   // 0.64 MB
    const size_t rs_bytes   = ((size_t)(MOUT + 1) * sizeof(int) + 15) & ~15ul; // 160 KB
    const size_t wt_bytes   = (size_t)KFDIM * COUT * sizeof(_Float16);         // 60 KB
    const size_t full_bytes = feat_bytes + pts4_bytes + op4_bytes + rs_bytes
                            + wt_bytes;                                        // ~4.1 MB

    if (ws_size >= full_bytes) {
        char* p = (char*)d_ws;
        _Float16* feat_i    = (_Float16*)p;  p += feat_bytes;
        float4*   points4   = (float4*)p;    p += pts4_bytes;
        float4*   op4       = (float4*)p;    p += op4_bytes;
        int*      row_start = (int*)p;       p += rs_bytes;
        _Float16* w_t       = (_Float16*)p;

        preprocess_all<<<PRE_BLKS, 256, 0, stream>>>(
            features, feat_i, points, points4, output_points, op4,
            seg_ids, row_start, k_values, w_t);
        kpconv_fused2<<<MOUT / 16, 256, 0, stream>>>(
            points4, feat_i, op4, nbr_idx, row_start, k_points, w_t, out);
    } else {
        _Float16* agg_g = (_Float16*)d_ws;   // needs 38.4 MB
        kpconv_agg_fallback<<<MOUT / 4, 256, 0, stream>>>(
            points, features, output_points, nbr_idx, seg_ids, k_points, agg_g);
        kpconv_gemm_plain<<<MOUT / 32, 256, 0, stream>>>(agg_g, k_values, out);
    }
}

// Round 6
// 112.425 us; speedup vs baseline: 1.2041x; 1.2041x over previous
//
#include <hip/hip_runtime.h>

typedef __attribute__((ext_vector_type(8))) short bf16x8;
typedef __attribute__((ext_vector_type(8))) _Float16 f16x8;
typedef __attribute__((ext_vector_type(4))) float f32x4;
typedef __attribute__((ext_vector_type(4))) _Float16 f16x4;
typedef __attribute__((ext_vector_type(2))) _Float16 f16x2;

#define NPTS   40000
#define MOUT   40000
#define EDG    500000
#define FIN    32
#define COUT   64
#define KP     15
#define KFDIM  (KP * FIN)          // 480
#define EXTENT 0.6f

// Phase-1 wave-private staging (R12-proven strides):
#define FSTRIDE 112
#define WSTRIDE 40
#define WAVE_LDS (16 * FSTRIDE + 16 * WSTRIDE)    // 2432 B/wave
// Block agg tile rows x 488 f16 (976B rows = 61*16B, conflict-free b128)
#define ASTR 488
// R19: segments per block 16 -> 8 (2 per wave). ONLY structural change vs R16.
#define SEGB 8

#define FEAT_BLKS  (NPTS * FIN / 1024)            // 1250
#define PTS_BLKS   ((NPTS + 255) / 256)           // 157
#define OP_BLKS    ((MOUT + 255) / 256)           // 157
#define ROW_BLKS   ((EDG + 255) / 256)            // 1954
#define WT_BLKS    (KFDIM * COUT / 256)           // 120
#define PRE_BLKS   (FEAT_BLKS + PTS_BLKS + OP_BLKS + ROW_BLKS + WT_BLKS)

__device__ __forceinline__ short f2bf(float x) {
    union { float f; unsigned u; } v; v.f = x;
    unsigned r = (v.u + 0x7fffu + ((v.u >> 16) & 1u)) >> 16;
    return (short)r;
}

// ============================================================================
// Preprocess (ONE launch, branch by block range) — unchanged.
// ============================================================================
__global__ __launch_bounds__(256) void preprocess_all(
    const float* __restrict__ features, _Float16* __restrict__ feat_i,
    const float* __restrict__ pts, float4* __restrict__ p4,
    const float* __restrict__ opts, float4* __restrict__ op4,
    const int* __restrict__ seg_ids, int* __restrict__ row_start,
    const float* __restrict__ k_values, _Float16* __restrict__ w_t)
{
    const int bid = blockIdx.x;
    if (bid < FEAT_BLKS) {
        const int d0 = (bid * 256 + threadIdx.x) * 4;
        #pragma unroll
        for (int u = 0; u < 4; ++u) {
            const int d = d0 + u;
            const int p = d >> 5, q = d & 31;
            const int fp = q >> 1, h = q & 1;
            feat_i[d] = (_Float16)features[p * FIN + fp + 16 * h];
        }
    } else if (bid < FEAT_BLKS + PTS_BLKS) {
        const int i = (bid - FEAT_BLKS) * 256 + threadIdx.x;
        if (i < NPTS) {
            const float* p = pts + 3 * i;
            p4[i] = make_float4(p[0], p[1], p[2], 0.f);
        }
    } else if (bid < FEAT_BLKS + PTS_BLKS + OP_BLKS) {
        const int i = (bid - FEAT_BLKS - PTS_BLKS) * 256 + threadIdx.x;
        if (i < MOUT) {
            const float* p = opts + 3 * i;
            op4[i] = make_float4(p[0], p[1], p[2], 0.f);
        }
    } else if (bid < FEAT_BLKS + PTS_BLKS + OP_BLKS + ROW_BLKS) {
        const int e = (bid - FEAT_BLKS - PTS_BLKS - OP_BLKS) * 256 + threadIdx.x;
        if (e >= EDG) return;
        const int cur  = seg_ids[e];
        const int prev = (e == 0) ? -1 : seg_ids[e - 1];
        for (int m = prev + 1; m <= cur; ++m) row_start[m] = e;
        if (e == EDG - 1)
            for (int m = cur + 1; m <= MOUT; ++m) row_start[m] = EDG;
    } else {
        const int d = (bid - FEAT_BLKS - PTS_BLKS - OP_BLKS - ROW_BLKS) * 256
                      + threadIdx.x;                 // 0 .. 30719
        const int c = d / KFDIM, r = d % KFDIM;
        const int k = r >> 5, q = r & 31;
        const int fp = q >> 1, h = q & 1;
        w_t[d] = (_Float16)k_values[(k * FIN + fp + 16 * h) * COUT + c];
    }
}

// ============================================================================
// Fused kernel — R16 structure verbatim, ONE change (R19): block = 8 segments,
// 2 segments/wave sequentially (was 16 / 4). Halves the per-wave serial
// chain that R15/R16 empirically validated as the bottleneck (~3us per
// ~300cy removed); doubles block count (5000) for better balance.
// R17/R18 post-mortem: rebuilt step engines regress (exposed VMEM latency /
// select-chain overhead); the R16 per-step code is kept byte-identical.
// Phase 2 unchanged: A-rows 8-15 read unwritten aggT (garbage) -> only
// affects D-rows 8-15 which are never stored; rows 0-7 clean.
// (256,5), LDS 25.3KB (aggT kept at 16 rows for read safety) -> 5 blocks/CU.
// Tripwire: >=102us -> R16 verbatim is final; pivot to fixed-cost side.
// ============================================================================
__global__ __launch_bounds__(256, 5) void kpconv_fused2(
    const float4* __restrict__ points4,
    const _Float16* __restrict__ feat_i,
    const float4* __restrict__ op4,
    const int*   __restrict__ nbr_idx,
    const int*   __restrict__ row_start,
    const float* __restrict__ k_points,
    const _Float16* __restrict__ w_t,
    float* __restrict__ out)
{
    __shared__ __align__(16) _Float16 aggT[16 * ASTR];          // 15616 B
    __shared__ __align__(16) unsigned char stage[4 * WAVE_LDS]; //  9728 B

    const int tid  = threadIdx.x;
    const int wave = tid >> 6;
    const int lane = tid & 63;
    const int quad = lane >> 4;
    const int l16  = lane & 15;
    const int esl  = lane >> 2;       // edge slot 0..15
    const int kg   = lane & 3;        // kgroup / feat-chunk index
    const int m0   = blockIdx.x * SEGB;

    unsigned char* fbase = stage + wave * WAVE_LDS;
    unsigned char* wbase = fbase + 16 * FSTRIDE;

    // per-lane kernel points (kgroup role)
    float kx[4], ky[4], kz[4];
    #pragma unroll
    for (int t = 0; t < 4; ++t) {
        const int k  = kg * 4 + t;
        const int kk = k < KP ? k : 0;
        kx[t] = k_points[kk * 3 + 0];
        ky[t] = k_points[kk * 3 + 1];
        kz[t] = k_points[kk * 3 + 2];
    }
    const float inv_ext = 1.f / EXTENT;

    // ---- segment bounds for this wave's 2 segments (contiguous edge range)
    int rs[3];
    #pragma unroll
    for (int i = 0; i < 3; ++i) rs[i] = row_start[m0 + wave * 2 + i];

    // next-nonempty-segment start cascade; sentinel = rs[2] (never consumed)
    int nstart[2];
    nstart[1] = rs[2];
    nstart[0] = (rs[1] < rs[2]) ? rs[1] : rs[2];
    const int fstart = (rs[0] < rs[1]) ? rs[0] : nstart[0];

    // ---- nbr window + prefetch state ----
    int wb = -0x40000000;     // forces initial window load
    int nbrreg = 0;
    uint4  fc_n = {0, 0, 0, 0};
    float4 p_n  = make_float4(0.f, 0.f, 0.f, 0.f);

    // prefetch gathers for step at uniform edge offset `es`
    auto pref = [&](int es) {
        if (es + 15 > wb + 63) {                 // wave-uniform slide
            wb = es;
            const int a = wb + lane;
            nbrreg = nbr_idx[a < EDG ? a : EDG - 1];
        }
        const int e  = es + esl;                 // <= wb+63 by construction
        const int nb = __shfl(nbrreg, e - wb);
        fc_n = *(const uint4*)(feat_i + nb * FIN + kg * 8);
        p_n  = ((const float4*)points4)[nb];
    };

    pref(fstart);   // first step of first nonempty segment (or dummy)

    // ---- Phase 1: 2 segments, pipelined step stream ----
    #pragma unroll
    for (int j = 0; j < 2; ++j) {
        const int e0 = rs[j];
        const int e1 = rs[j + 1];
        const float4 o = op4[m0 + wave * 2 + j];

        f32x4 c_lo = {0.f, 0.f, 0.f, 0.f};
        f32x4 c_hi = {0.f, 0.f, 0.f, 0.f};

        for (int es = e0; es < e1; es += 16) {
            // take current step's prefetched data, then issue next step's
            const uint4  fc = fc_n;
            const float4 p  = p_n;
            const int nes = (es + 16 < e1) ? es + 16 : nstart[j];
            pref(nes);

            // ---- consume (identical to proven R12 code) ----
            *(uint4*)(fbase + esl * FSTRIDE + kg * 16) = fc;

            const float rx = p.x - o.x, ry = p.y - o.y, rz = p.z - o.z;
            const bool evalid = (es + esl) < e1;
            #pragma unroll
            for (int t = 0; t < 4; ++t) {
                const float dx = rx - kx[t], dy = ry - ky[t], dz = rz - kz[t];
                float w = 1.f - sqrtf(dx * dx + dy * dy + dz * dz) * inv_ext;
                w = w > 0.f ? w : 0.f;
                if (!evalid || (kg * 4 + t) >= KP) w = 0.f;
                *(_Float16*)(wbase + (kg * 4 + t) * WSTRIDE + esl * 2) = (_Float16)w;
            }

            const f16x4 af = *(const f16x4*)(wbase + l16 * WSTRIDE + quad * 8);
            f16x2 w2[4];
            #pragma unroll
            for (int jj = 0; jj < 4; ++jj)
                w2[jj] = *(const f16x2*)(fbase + (quad * 4 + jj) * FSTRIDE + l16 * 4);
            const f16x4 blo = {w2[0][0], w2[1][0], w2[2][0], w2[3][0]};
            const f16x4 bhi = {w2[0][1], w2[1][1], w2[2][1], w2[3][1]};

            c_lo = __builtin_amdgcn_mfma_f32_16x16x16f16(af, blo, c_lo, 0, 0, 0);
            c_hi = __builtin_amdgcn_mfma_f32_16x16x16f16(af, bhi, c_hi, 0, 0, 0);
        }

        // D -> agg tile row (interleaved kf order): byte = k*64 + l16*4
        _Float16* dst = aggT + (wave * 2 + j) * ASTR;
        #pragma unroll
        for (int r = 0; r < 4; ++r) {
            const int krow = quad * 4 + r;
            if (krow < KP) {
                f16x2 v = {(_Float16)c_lo[r], (_Float16)c_hi[r]};
                *(f16x2*)(dst + krow * 32 + 2 * l16) = v;
            }
        }
    }

    __syncthreads();

    // ---- Phase 2: C[8 segs x 16 cols] per wave, B in-loop from w_t ----
    // A-rows 8-15 are unwritten LDS (garbage) -> D-rows 8-15 garbage, unstored.
    const int bcol = wave * 16 + l16;
    const _Float16* wrow = w_t + (size_t)bcol * KFDIM + quad * 8;
    const _Float16* arow = aggT + l16 * ASTR + quad * 8;

    f32x4 c = {0.f, 0.f, 0.f, 0.f};
    #pragma unroll
    for (int s = 0; s < 15; ++s) {
        const f16x8 a = *(const f16x8*)(arow + 32 * s);
        const f16x8 b = *(const f16x8*)(wrow + 32 * s);
        c = __builtin_amdgcn_mfma_f32_16x16x32_f16(a, b, c, 0, 0, 0);
    }

    // C/D: col = lane&15 (-> bcol), row = quad*4 + r (= local segment, <8 valid)
    #pragma unroll
    for (int r = 0; r < 4; ++r) {
        const int seg = quad * 4 + r;
        if (seg < SEGB)
            out[(m0 + seg) * COUT + bcol] = c[r];
    }
}

// ============================================================================
// Fallback (small ws, needs 38.4 MB): binary-search K=32 agg + plain gemm.
// ============================================================================
__global__ __launch_bounds__(256, 4) void kpconv_agg_fallback(
    const float* __restrict__ points,
    const float* __restrict__ features,
    const float* __restrict__ output_points,
    const int*   __restrict__ nbr_idx,
    const int*   __restrict__ seg_ids,
    const float* __restrict__ k_points,
    _Float16* __restrict__ agg_g)
{
    __shared__ int seg_start[5];

    const int tid = threadIdx.x;
    const int m0  = blockIdx.x * 4;

    if (tid <= 4) {
        const int target = m0 + tid;
        int lo = 0, hi = EDG;
        while (lo < hi) {
            int mid = (lo + hi) >> 1;
            if (seg_ids[mid] < target) lo = mid + 1; else hi = mid;
        }
        seg_start[tid] = lo;
    }
    __syncthreads();

    const int wave = tid >> 6;
    const int lane = tid & 63;
    const int quad = lane >> 4;
    const int l16  = lane & 15;

    const int m = m0 + wave;
    const float ox = output_points[m * 3 + 0];
    const float oy = output_points[m * 3 + 1];
    const float oz = output_points[m * 3 + 2];

    const int myk = l16 < KP ? l16 : 0;
    const float kpx = k_points[myk * 3 + 0];
    const float kpy = k_points[myk * 3 + 1];
    const float kpz = k_points[myk * 3 + 2];
    const float inv_ext = 1.f / EXTENT;

    const int e0 = seg_start[wave], e1 = seg_start[wave + 1];

    f32x4 c_lo = {0.f, 0.f, 0.f, 0.f};
    f32x4 c_hi = {0.f, 0.f, 0.f, 0.f};

    for (int es = e0; es < e1; es += 32) {
        const int last = e1 - 1;
        const int ebase = es + quad * 8;

        int nb[8];
        #pragma unroll
        for (int j = 0; j < 8; ++j) {
            const int e = ebase + j;
            nb[j] = nbr_idx[e < e1 ? e : last];
        }

        bf16x8 afrag, blo, bhi;
        #pragma unroll
        for (int j = 0; j < 8; ++j) {
            const float* pp = points + nb[j] * 3;
            const float rx = pp[0] - ox;
            const float ry = pp[1] - oy;
            const float rz = pp[2] - oz;
            const float dx = rx - kpx, dy = ry - kpy, dz = rz - kpz;
            const float d2 = dx * dx + dy * dy + dz * dz;
            float w = 1.f - sqrtf(d2) * inv_ext;
            w = w > 0.f ? w : 0.f;
            if (l16 >= KP || ebase + j >= e1) w = 0.f;
            afrag[j] = f2bf(w);
        }

        #pragma unroll
        for (int j = 0; j < 8; ++j) {
            const float* fp = features + nb[j] * FIN + l16;
            blo[j] = f2bf(fp[0]);
            bhi[j] = f2bf(fp[16]);
        }

        c_lo = __builtin_amdgcn_mfma_f32_16x16x32_bf16(afrag, blo, c_lo, 0, 0, 0);
        c_hi = __builtin_amdgcn_mfma_f32_16x16x32_bf16(afrag, bhi, c_hi, 0, 0, 0);
    }

    _Float16* dst = agg_g + (size_t)m * KFDIM;
    #pragma unroll
    for (int r = 0; r < 4; ++r) {
        const int krow = quad * 4 + r;
        if (krow < KP) {
            dst[krow * FIN + l16]      = (_Float16)c_lo[r];
            dst[krow * FIN + 16 + l16] = (_Float16)c_hi[r];
        }
    }
}

__global__ __launch_bounds__(256, 4) void kpconv_gemm_plain(
    const _Float16* __restrict__ agg_g,
    const float* __restrict__ k_values,
    float* __restrict__ out)
{
    const int tid  = threadIdx.x;
    const int wave = tid >> 6;
    const int lane = tid & 63;
    const int quad = lane >> 4;
    const int l16  = lane & 15;
    const int m0   = blockIdx.x * 32;
    const int bcol = wave * 16 + l16;

    f16x8 bfr[15];
    #pragma unroll
    for (int s = 0; s < 15; ++s) {
        #pragma unroll
        for (int j = 0; j < 8; ++j)
            bfr[s][j] = (_Float16)k_values[(32 * s + quad * 8 + j) * COUT + bcol];
    }

    const _Float16* arow0 = agg_g + (size_t)(m0 + l16) * KFDIM + quad * 8;
    const _Float16* arow1 = arow0 + 16 * KFDIM;

    f32x4 c0 = {0.f, 0.f, 0.f, 0.f};
    f32x4 c1 = {0.f, 0.f, 0.f, 0.f};
    #pragma unroll
    for (int s = 0; s < 15; ++s) {
        const f16x8 a0 = *(const f16x8*)(arow0 + 32 * s);
        const f16x8 a1 = *(const f16x8*)(arow1 + 32 * s);
        c0 = __builtin_amdgcn_mfma_f32_16x16x32_f16(a0, bfr[s], c0, 0, 0, 0);
        c1 = __builtin_amdgcn_mfma_f32_16x16x32_f16(a1, bfr[s], c1, 0, 0, 0);
    }

    #pragma unroll
    for (int r = 0; r < 4; ++r) {
        out[(m0 + quad * 4 + r) * COUT + bcol]      = c0[r];
        out[(m0 + 16 + quad * 4 + r) * COUT + bcol] = c1[r];
    }
}

extern "C" void kernel_launch(void* const* d_in, const int* in_sizes, int n_in,
                              void* d_out, int out_size, void* d_ws, size_t ws_size,
                              hipStream_t stream) {
    const float* points        = (const float*)d_in[0];
    const float* features      = (const float*)d_in[1];
    const float* output_points = (const float*)d_in[2];
    const int*   nbr_idx       = (const int*)d_in[3];
    const int*   seg_ids       = (const int*)d_in[4];
    const float* k_points      = (const float*)d_in[5];
    const float* k_values      = (const float*)d_in[6];
    float* out = (float*)d_out;

    const size_t feat_bytes = (size_t)NPTS * FIN * sizeof(_Float16);           // 2.56 MB
    const size_t pts4_bytes = (size_t)NPTS * sizeof(float4);                   // 0.64 MB
    const size_t op4_bytes  = (size_t)MOUT * sizeof(float4);                   // 0.64 MB
    const size_t rs_bytes   = ((size_t)(MOUT + 1) * sizeof(int) + 15) & ~15ul; // 160 KB
    const size_t wt_bytes   = (size_t)KFDIM * COUT * sizeof(_Float16);         // 60 KB
    const size_t full_bytes = feat_bytes + pts4_bytes + op4_bytes + rs_bytes
                            + wt_bytes;                                        // ~4.1 MB

    if (ws_size >= full_bytes) {
        char* p = (char*)d_ws;
        _Float16* feat_i    = (_Float16*)p;  p += feat_bytes;
        float4*   points4   = (float4*)p;    p += pts4_bytes;
        float4*   op4       = (float4*)p;    p += op4_bytes;
        int*      row_start = (int*)p;       p += rs_bytes;
        _Float16* w_t       = (_Float16*)p;

        preprocess_all<<<PRE_BLKS, 256, 0, stream>>>(
            features, feat_i, points, points4, output_points, op4,
            seg_ids, row_start, k_values, w_t);
        kpconv_fused2<<<MOUT / SEGB, 256, 0, stream>>>(
            points4, feat_i, op4, nbr_idx, row_start, k_points, w_t, out);
    } else {
        _Float16* agg_g = (_Float16*)d_ws;   // needs 38.4 MB
        kpconv_agg_fallback<<<MOUT / 4, 256, 0, stream>>>(
            points, features, output_points, nbr_idx, seg_ids, k_points, agg_g);
        kpconv_gemm_plain<<<MOUT / 32, 256, 0, stream>>>(agg_g, k_values, out);
    }
}

// Round 7
// 104.930 us; speedup vs baseline: 1.2901x; 1.0714x over previous
//
#include <hip/hip_runtime.h>

typedef __attribute__((ext_vector_type(8))) short bf16x8;
typedef __attribute__((ext_vector_type(8))) _Float16 f16x8;
typedef __attribute__((ext_vector_type(4))) float f32x4;
typedef __attribute__((ext_vector_type(4))) _Float16 f16x4;
typedef __attribute__((ext_vector_type(2))) _Float16 f16x2;

#define NPTS   40000
#define MOUT   40000
#define EDG    500000
#define FIN    32
#define COUT   64
#define KP     15
#define KFDIM  (KP * FIN)          // 480
#define EXTENT 0.6f

// Phase-1 wave-private staging (R12-proven strides):
#define FSTRIDE 112
#define WSTRIDE 40
#define WAVE_LDS (16 * FSTRIDE + 16 * WSTRIDE)    // 2432 B/wave
// Block agg tile: 16 segments x 488 f16 (976B rows = 61*16B, conflict-free b128)
#define ASTR 488

#define FEAT_BLKS  (NPTS * FIN / 1024)            // 1250
#define PTS_BLKS   ((NPTS + 255) / 256)           // 157
#define OP_BLKS    ((MOUT + 255) / 256)           // 157
#define ROW_BLKS   ((EDG + 255) / 256)            // 1954
#define WT_BLKS    (KFDIM * COUT / 256)           // 120
#define PRE_BLKS   (FEAT_BLKS + PTS_BLKS + OP_BLKS + ROW_BLKS + WT_BLKS)

__device__ __forceinline__ short f2bf(float x) {
    union { float f; unsigned u; } v; v.f = x;
    unsigned r = (v.u + 0x7fffu + ((v.u >> 16) & 1u)) >> 16;
    return (short)r;
}

// ============================================================================
// Preprocess (ONE launch, branch by block range) — unchanged.
// ============================================================================
__global__ __launch_bounds__(256) void preprocess_all(
    const float* __restrict__ features, _Float16* __restrict__ feat_i,
    const float* __restrict__ pts, float4* __restrict__ p4,
    const float* __restrict__ opts, float4* __restrict__ op4,
    const int* __restrict__ seg_ids, int* __restrict__ row_start,
    const float* __restrict__ k_values, _Float16* __restrict__ w_t)
{
    const int bid = blockIdx.x;
    if (bid < FEAT_BLKS) {
        const int d0 = (bid * 256 + threadIdx.x) * 4;
        #pragma unroll
        for (int u = 0; u < 4; ++u) {
            const int d = d0 + u;
            const int p = d >> 5, q = d & 31;
            const int fp = q >> 1, h = q & 1;
            feat_i[d] = (_Float16)features[p * FIN + fp + 16 * h];
        }
    } else if (bid < FEAT_BLKS + PTS_BLKS) {
        const int i = (bid - FEAT_BLKS) * 256 + threadIdx.x;
        if (i < NPTS) {
            const float* p = pts + 3 * i;
            p4[i] = make_float4(p[0], p[1], p[2], 0.f);
        }
    } else if (bid < FEAT_BLKS + PTS_BLKS + OP_BLKS) {
        const int i = (bid - FEAT_BLKS - PTS_BLKS) * 256 + threadIdx.x;
        if (i < MOUT) {
            const float* p = opts + 3 * i;
            op4[i] = make_float4(p[0], p[1], p[2], 0.f);
        }
    } else if (bid < FEAT_BLKS + PTS_BLKS + OP_BLKS + ROW_BLKS) {
        const int e = (bid - FEAT_BLKS - PTS_BLKS - OP_BLKS) * 256 + threadIdx.x;
        if (e >= EDG) return;
        const int cur  = seg_ids[e];
        const int prev = (e == 0) ? -1 : seg_ids[e - 1];
        for (int m = prev + 1; m <= cur; ++m) row_start[m] = e;
        if (e == EDG - 1)
            for (int m = cur + 1; m <= MOUT; ++m) row_start[m] = EDG;
    } else {
        const int d = (bid - FEAT_BLKS - PTS_BLKS - OP_BLKS - ROW_BLKS) * 256
                      + threadIdx.x;                 // 0 .. 30719
        const int c = d / KFDIM, r = d % KFDIM;
        const int k = r >> 5, q = r & 31;
        const int fp = q >> 1, h = q & 1;
        w_t[d] = (_Float16)k_values[(k * FIN + fp + 16 * h) * COUT + c];
    }
}

// ============================================================================
// Fused kernel — R16 structure VERBATIM (proven 101.9us wall, fused2 ~30us),
// R20: three chain-local, bit-identical micro-cuts, nothing structural:
//  (1) (256,6): VGPR ~40-48 -> LDS is the only occupancy limiter
//      (6 x 25.3KB = 152KB < 160KB). +20% resident waves, latency-bound.
//  (2) KP-mask poison-hoist: k=15 lane coords = 1e9 -> w = 1-sqrt(huge)/ext
//      < 0 -> clamped to exactly 0.0f. Removes 4 cmp/sel per step.
//  (3) nb clamp dropped: e = es+esl <= wb+63 is in-window by the slide
//      condition; out-of-segment gathers are masked by w=0 (0*finite=0).
// R19 lesson (fused2 44us @ 2 seg/wave vs 30us @ 4): per-wave overhead x
// wave count dominates over chain length; keep 4 seg/wave, 16 seg/block.
// Tripwire: >=102us -> structure is at local floor; pivot or settle.
// ============================================================================
__global__ __launch_bounds__(256, 6) void kpconv_fused2(
    const float4* __restrict__ points4,
    const _Float16* __restrict__ feat_i,
    const float4* __restrict__ op4,
    const int*   __restrict__ nbr_idx,
    const int*   __restrict__ row_start,
    const float* __restrict__ k_points,
    const _Float16* __restrict__ w_t,
    float* __restrict__ out)
{
    __shared__ __align__(16) _Float16 aggT[16 * ASTR];          // 15616 B
    __shared__ __align__(16) unsigned char stage[4 * WAVE_LDS]; //  9728 B

    const int tid  = threadIdx.x;
    const int wave = tid >> 6;
    const int lane = tid & 63;
    const int quad = lane >> 4;
    const int l16  = lane & 15;
    const int esl  = lane >> 2;       // edge slot 0..15
    const int kg   = lane & 3;        // kgroup / feat-chunk index
    const int m0   = blockIdx.x * 16;

    unsigned char* fbase = stage + wave * WAVE_LDS;
    unsigned char* wbase = fbase + 16 * FSTRIDE;

    // per-lane kernel points (kgroup role); k >= KP poisoned so that
    // w = 1 - sqrt(huge)*inv_ext < 0 -> clamps to exactly 0.0f (bit-identical
    // to the old in-loop mask, without the per-step compares).
    float kx[4], ky[4], kz[4];
    #pragma unroll
    for (int t = 0; t < 4; ++t) {
        const int k  = kg * 4 + t;
        const bool v = (k < KP);
        const int kk = v ? k : 0;
        kx[t] = v ? k_points[kk * 3 + 0] : 1e9f;
        ky[t] = v ? k_points[kk * 3 + 1] : 1e9f;
        kz[t] = v ? k_points[kk * 3 + 2] : 1e9f;
    }
    const float inv_ext = 1.f / EXTENT;

    // ---- segment bounds for this wave's 4 segments (contiguous edge range)
    int rs[5];
    #pragma unroll
    for (int i = 0; i < 5; ++i) rs[i] = row_start[m0 + wave * 4 + i];

    // next-nonempty-segment start cascade; sentinel = rs[4] (never consumed)
    int nstart[4];
    nstart[3] = rs[4];
    nstart[2] = (rs[3] < rs[4]) ? rs[3] : rs[4];
    nstart[1] = (rs[2] < rs[3]) ? rs[2] : nstart[2];
    nstart[0] = (rs[1] < rs[2]) ? rs[1] : nstart[1];
    const int fstart = (rs[0] < rs[1]) ? rs[0] : nstart[0];

    // ---- nbr window + prefetch state ----
    int wb = -0x40000000;     // forces initial window load
    int nbrreg = 0;
    uint4  fc_n = {0, 0, 0, 0};
    float4 p_n  = make_float4(0.f, 0.f, 0.f, 0.f);

    // prefetch gathers for step at uniform edge offset `es`
    auto pref = [&](int es) {
        if (es + 15 > wb + 63) {                 // wave-uniform slide
            wb = es;
            const int a = wb + lane;
            nbrreg = nbr_idx[a < EDG ? a : EDG - 1];
        }
        // e <= wb+63 by the slide condition; out-of-segment edges are real
        // indices whose contribution is masked by w=0 downstream.
        const int nb = __shfl(nbrreg, es + esl - wb);
        fc_n = *(const uint4*)(feat_i + nb * FIN + kg * 8);
        p_n  = ((const float4*)points4)[nb];
    };

    pref(fstart);   // first step of first nonempty segment (or dummy)

    // ---- Phase 1: 4 segments, pipelined step stream ----
    #pragma unroll
    for (int j = 0; j < 4; ++j) {
        const int e0 = rs[j];
        const int e1 = rs[j + 1];
        const float4 o = op4[m0 + wave * 4 + j];

        f32x4 c_lo = {0.f, 0.f, 0.f, 0.f};
        f32x4 c_hi = {0.f, 0.f, 0.f, 0.f};

        for (int es = e0; es < e1; es += 16) {
            // take current step's prefetched data, then issue next step's
            const uint4  fc = fc_n;
            const float4 p  = p_n;
            const int nes = (es + 16 < e1) ? es + 16 : nstart[j];
            pref(nes);

            // ---- consume (identical to proven R12 code) ----
            *(uint4*)(fbase + esl * FSTRIDE + kg * 16) = fc;

            const float rx = p.x - o.x, ry = p.y - o.y, rz = p.z - o.z;
            const bool evalid = (es + esl) < e1;
            #pragma unroll
            for (int t = 0; t < 4; ++t) {
                const float dx = rx - kx[t], dy = ry - ky[t], dz = rz - kz[t];
                float w = 1.f - sqrtf(dx * dx + dy * dy + dz * dz) * inv_ext;
                w = w > 0.f ? w : 0.f;
                if (!evalid) w = 0.f;
                *(_Float16*)(wbase + (kg * 4 + t) * WSTRIDE + esl * 2) = (_Float16)w;
            }

            const f16x4 af = *(const f16x4*)(wbase + l16 * WSTRIDE + quad * 8);
            f16x2 w2[4];
            #pragma unroll
            for (int jj = 0; jj < 4; ++jj)
                w2[jj] = *(const f16x2*)(fbase + (quad * 4 + jj) * FSTRIDE + l16 * 4);
            const f16x4 blo = {w2[0][0], w2[1][0], w2[2][0], w2[3][0]};
            const f16x4 bhi = {w2[0][1], w2[1][1], w2[2][1], w2[3][1]};

            c_lo = __builtin_amdgcn_mfma_f32_16x16x16f16(af, blo, c_lo, 0, 0, 0);
            c_hi = __builtin_amdgcn_mfma_f32_16x16x16f16(af, bhi, c_hi, 0, 0, 0);
        }

        // D -> agg tile row (interleaved kf order): byte = k*64 + l16*4
        _Float16* dst = aggT + (wave * 4 + j) * ASTR;
        #pragma unroll
        for (int r = 0; r < 4; ++r) {
            const int krow = quad * 4 + r;
            if (krow < KP) {
                f16x2 v = {(_Float16)c_lo[r], (_Float16)c_hi[r]};
                *(f16x2*)(dst + krow * 32 + 2 * l16) = v;
            }
        }
    }

    __syncthreads();

    // ---- Phase 2: C[16 segs x 16 cols] per wave, B in-loop from w_t ----
    const int bcol = wave * 16 + l16;
    const _Float16* wrow = w_t + (size_t)bcol * KFDIM + quad * 8;
    const _Float16* arow = aggT + l16 * ASTR + quad * 8;

    f32x4 c = {0.f, 0.f, 0.f, 0.f};
    #pragma unroll
    for (int s = 0; s < 15; ++s) {
        const f16x8 a = *(const f16x8*)(arow + 32 * s);
        const f16x8 b = *(const f16x8*)(wrow + 32 * s);
        c = __builtin_amdgcn_mfma_f32_16x16x32_f16(a, b, c, 0, 0, 0);
    }

    // C/D: col = lane&15 (-> bcol), row = quad*4 + r (= local segment)
    #pragma unroll
    for (int r = 0; r < 4; ++r)
        out[(m0 + quad * 4 + r) * COUT + bcol] = c[r];
}

// ============================================================================
// Fallback (small ws, needs 38.4 MB): binary-search K=32 agg + plain gemm.
// ============================================================================
__global__ __launch_bounds__(256, 4) void kpconv_agg_fallback(
    const float* __restrict__ points,
    const float* __restrict__ features,
    const float* __restrict__ output_points,
    const int*   __restrict__ nbr_idx,
    const int*   __restrict__ seg_ids,
    const float* __restrict__ k_points,
    _Float16* __restrict__ agg_g)
{
    __shared__ int seg_start[5];

    const int tid = threadIdx.x;
    const int m0  = blockIdx.x * 4;

    if (tid <= 4) {
        const int target = m0 + tid;
        int lo = 0, hi = EDG;
        while (lo < hi) {
            int mid = (lo + hi) >> 1;
            if (seg_ids[mid] < target) lo = mid + 1; else hi = mid;
        }
        seg_start[tid] = lo;
    }
    __syncthreads();

    const int wave = tid >> 6;
    const int lane = tid & 63;
    const int quad = lane >> 4;
    const int l16  = lane & 15;

    const int m = m0 + wave;
    const float ox = output_points[m * 3 + 0];
    const float oy = output_points[m * 3 + 1];
    const float oz = output_points[m * 3 + 2];

    const int myk = l16 < KP ? l16 : 0;
    const float kpx = k_points[myk * 3 + 0];
    const float kpy = k_points[myk * 3 + 1];
    const float kpz = k_points[myk * 3 + 2];
    const float inv_ext = 1.f / EXTENT;

    const int e0 = seg_start[wave], e1 = seg_start[wave + 1];

    f32x4 c_lo = {0.f, 0.f, 0.f, 0.f};
    f32x4 c_hi = {0.f, 0.f, 0.f, 0.f};

    for (int es = e0; es < e1; es += 32) {
        const int last = e1 - 1;
        const int ebase = es + quad * 8;

        int nb[8];
        #pragma unroll
        for (int j = 0; j < 8; ++j) {
            const int e = ebase + j;
            nb[j] = nbr_idx[e < e1 ? e : last];
        }

        bf16x8 afrag, blo, bhi;
        #pragma unroll
        for (int j = 0; j < 8; ++j) {
            const float* pp = points + nb[j] * 3;
            const float rx = pp[0] - ox;
            const float ry = pp[1] - oy;
            const float rz = pp[2] - oz;
            const float dx = rx - kpx, dy = ry - kpy, dz = rz - kpz;
            const float d2 = dx * dx + dy * dy + dz * dz;
            float w = 1.f - sqrtf(d2) * inv_ext;
            w = w > 0.f ? w : 0.f;
            if (l16 >= KP || ebase + j >= e1) w = 0.f;
            afrag[j] = f2bf(w);
        }

        #pragma unroll
        for (int j = 0; j < 8; ++j) {
            const float* fp = features + nb[j] * FIN + l16;
            blo[j] = f2bf(fp[0]);
            bhi[j] = f2bf(fp[16]);
        }

        c_lo = __builtin_amdgcn_mfma_f32_16x16x32_bf16(afrag, blo, c_lo, 0, 0, 0);
        c_hi = __builtin_amdgcn_mfma_f32_16x16x32_bf16(afrag, bhi, c_hi, 0, 0, 0);
    }

    _Float16* dst = agg_g + (size_t)m * KFDIM;
    #pragma unroll
    for (int r = 0; r < 4; ++r) {
        const int krow = quad * 4 + r;
        if (krow < KP) {
            dst[krow * FIN + l16]      = (_Float16)c_lo[r];
            dst[krow * FIN + 16 + l16] = (_Float16)c_hi[r];
        }
    }
}

__global__ __launch_bounds__(256, 4) void kpconv_gemm_plain(
    const _Float16* __restrict__ agg_g,
    const float* __restrict__ k_values,
    float* __restrict__ out)
{
    const int tid  = threadIdx.x;
    const int wave = tid >> 6;
    const int lane = tid & 63;
    const int quad = lane >> 4;
    const int l16  = lane & 15;
    const int m0   = blockIdx.x * 32;
    const int bcol = wave * 16 + l16;

    f16x8 bfr[15];
    #pragma unroll
    for (int s = 0; s < 15; ++s) {
        #pragma unroll
        for (int j = 0; j < 8; ++j)
            bfr[s][j] = (_Float16)k_values[(32 * s + quad * 8 + j) * COUT + bcol];
    }

    const _Float16* arow0 = agg_g + (size_t)(m0 + l16) * KFDIM + quad * 8;
    const _Float16* arow1 = arow0 + 16 * KFDIM;

    f32x4 c0 = {0.f, 0.f, 0.f, 0.f};
    f32x4 c1 = {0.f, 0.f, 0.f, 0.f};
    #pragma unroll
    for (int s = 0; s < 15; ++s) {
        const f16x8 a0 = *(const f16x8*)(arow0 + 32 * s);
        const f16x8 a1 = *(const f16x8*)(arow1 + 32 * s);
        c0 = __builtin_amdgcn_mfma_f32_16x16x32_f16(a0, bfr[s], c0, 0, 0, 0);
        c1 = __builtin_amdgcn_mfma_f32_16x16x32_f16(a1, bfr[s], c1, 0, 0, 0);
    }

    #pragma unroll
    for (int r = 0; r < 4; ++r) {
        out[(m0 + quad * 4 + r) * COUT + bcol]      = c0[r];
        out[(m0 + 16 + quad * 4 + r) * COUT + bcol] = c1[r];
    }
}

extern "C" void kernel_launch(void* const* d_in, const int* in_sizes, int n_in,
                              void* d_out, int out_size, void* d_ws, size_t ws_size,
                              hipStream_t stream) {
    const float* points        = (const float*)d_in[0];
    const float* features      = (const float*)d_in[1];
    const float* output_points = (const float*)d_in[2];
    const int*   nbr_idx       = (const int*)d_in[3];
    const int*   seg_ids       = (const int*)d_in[4];
    const float* k_points      = (const float*)d_in[5];
    const float* k_values      = (const float*)d_in[6];
    float* out = (float*)d_out;

    const size_t feat_bytes = (size_t)NPTS * FIN * sizeof(_Float16);           // 2.56 MB
    const size_t pts4_bytes = (size_t)NPTS * sizeof(float4);                   // 0.64 MB
    const size_t op4_bytes  = (size_t)MOUT * sizeof(float4);                   // 0.64 MB
    const size_t rs_bytes   = ((size_t)(MOUT + 1) * sizeof(int) + 15) & ~15ul; // 160 KB
    const size_t wt_bytes   = (size_t)KFDIM * COUT * sizeof(_Float16);         // 60 KB
    const size_t full_bytes = feat_bytes + pts4_bytes + op4_bytes + rs_bytes
                            + wt_bytes;                                        // ~4.1 MB

    if (ws_size >= full_bytes) {
        char* p = (char*)d_ws;
        _Float16* feat_i    = (_Float16*)p;  p += feat_bytes;
        float4*   points4   = (float4*)p;    p += pts4_bytes;
        float4*   op4       = (float4*)p;    p += op4_bytes;
        int*      row_start = (int*)p;       p += rs_bytes;
        _Float16* w_t       = (_Float16*)p;

        preprocess_all<<<PRE_BLKS, 256, 0, stream>>>(
            features, feat_i, points, points4, output_points, op4,
            seg_ids, row_start, k_values, w_t);
        kpconv_fused2<<<MOUT / 16, 256, 0, stream>>>(
            points4, feat_i, op4, nbr_idx, row_start, k_points, w_t, out);
    } else {
        _Float16* agg_g = (_Float16*)d_ws;   // needs 38.4 MB
        kpconv_agg_fallback<<<MOUT / 4, 256, 0, stream>>>(
            points, features, output_points, nbr_idx, seg_ids, k_points, agg_g);
        kpconv_gemm_plain<<<MOUT / 32, 256, 0, stream>>>(agg_g, k_values, out);
    }
}

// Round 8
// 102.406 us; speedup vs baseline: 1.3219x; 1.0246x over previous
//
#include <hip/hip_runtime.h>

typedef __attribute__((ext_vector_type(8))) short bf16x8;
typedef __attribute__((ext_vector_type(8))) _Float16 f16x8;
typedef __attribute__((ext_vector_type(4))) float f32x4;
typedef __attribute__((ext_vector_type(4))) _Float16 f16x4;
typedef __attribute__((ext_vector_type(2))) _Float16 f16x2;

#define NPTS   40000
#define MOUT   40000
#define EDG    500000
#define FIN    32
#define COUT   64
#define KP     15
#define KFDIM  (KP * FIN)          // 480
#define EXTENT 0.6f

// Phase-1 wave-private staging (R12-proven strides):
#define FSTRIDE 112
#define WSTRIDE 40
#define WAVE_LDS (16 * FSTRIDE + 16 * WSTRIDE)    // 2432 B/wave
// Block agg tile: 32 segments x 488 f16 (976B rows = 61*16B, conflict-free b128)
#define ASTR 488
// R21: 8 segments per wave, 32 per block (was 4/16). ONLY structural change
// vs R16. Rounds model fit to {R16 s=4: ~30us, R19 s=2: 44us}: fused2 =
// 16 + 56/s us -> s=8 predicts ~23us.
#define SEGW 8
#define SEGB 32

#define FEAT_BLKS  (NPTS * FIN / 1024)            // 1250
#define PTS_BLKS   ((NPTS + 255) / 256)           // 157
#define OP_BLKS    ((MOUT + 255) / 256)           // 157
#define ROW_BLKS   ((EDG + 255) / 256)            // 1954
#define WT_BLKS    (KFDIM * COUT / 256)           // 120
#define PRE_BLKS   (FEAT_BLKS + PTS_BLKS + OP_BLKS + ROW_BLKS + WT_BLKS)

__device__ __forceinline__ short f2bf(float x) {
    union { float f; unsigned u; } v; v.f = x;
    unsigned r = (v.u + 0x7fffu + ((v.u >> 16) & 1u)) >> 16;
    return (short)r;
}

// ============================================================================
// Preprocess (ONE launch, branch by block range) — unchanged.
// ============================================================================
__global__ __launch_bounds__(256) void preprocess_all(
    const float* __restrict__ features, _Float16* __restrict__ feat_i,
    const float* __restrict__ pts, float4* __restrict__ p4,
    const float* __restrict__ opts, float4* __restrict__ op4,
    const int* __restrict__ seg_ids, int* __restrict__ row_start,
    const float* __restrict__ k_values, _Float16* __restrict__ w_t)
{
    const int bid = blockIdx.x;
    if (bid < FEAT_BLKS) {
        const int d0 = (bid * 256 + threadIdx.x) * 4;
        #pragma unroll
        for (int u = 0; u < 4; ++u) {
            const int d = d0 + u;
            const int p = d >> 5, q = d & 31;
            const int fp = q >> 1, h = q & 1;
            feat_i[d] = (_Float16)features[p * FIN + fp + 16 * h];
        }
    } else if (bid < FEAT_BLKS + PTS_BLKS) {
        const int i = (bid - FEAT_BLKS) * 256 + threadIdx.x;
        if (i < NPTS) {
            const float* p = pts + 3 * i;
            p4[i] = make_float4(p[0], p[1], p[2], 0.f);
        }
    } else if (bid < FEAT_BLKS + PTS_BLKS + OP_BLKS) {
        const int i = (bid - FEAT_BLKS - PTS_BLKS) * 256 + threadIdx.x;
        if (i < MOUT) {
            const float* p = opts + 3 * i;
            op4[i] = make_float4(p[0], p[1], p[2], 0.f);
        }
    } else if (bid < FEAT_BLKS + PTS_BLKS + OP_BLKS + ROW_BLKS) {
        const int e = (bid - FEAT_BLKS - PTS_BLKS - OP_BLKS) * 256 + threadIdx.x;
        if (e >= EDG) return;
        const int cur  = seg_ids[e];
        const int prev = (e == 0) ? -1 : seg_ids[e - 1];
        for (int m = prev + 1; m <= cur; ++m) row_start[m] = e;
        if (e == EDG - 1)
            for (int m = cur + 1; m <= MOUT; ++m) row_start[m] = EDG;
    } else {
        const int d = (bid - FEAT_BLKS - PTS_BLKS - OP_BLKS - ROW_BLKS) * 256
                      + threadIdx.x;                 // 0 .. 30719
        const int c = d / KFDIM, r = d % KFDIM;
        const int k = r >> 5, q = r & 31;
        const int fp = q >> 1, h = q & 1;
        w_t[d] = (_Float16)k_values[(k * FIN + fp + 16 * h) * COUT + c];
    }
}

// ============================================================================
// Fused kernel — R16 per-step code VERBATIM; R21 = one parameter change:
// 8 segments/wave (32/block, grid 1250). Rationale: fused2 fits A + B/s
// (A~16us step work, B~56us per-wave setup x wave count; fit from R16/R19).
// s=8 halves wave count -> predicts ~23us. Cost: aggT 32 rows -> LDS 40KB,
// 4 blocks/CU (16 waves/CU vs 24) — accepted, occupancy proved non-binding
// in R20 ((256,6) bump was flat). Phase 2: two row-tiles per wave (mirrors
// proven kpconv_gemm_plain two-tile pattern).
// Tripwire: >=103us -> model wrong in this direction; revert to R16 final.
// ============================================================================
__global__ __launch_bounds__(256, 4) void kpconv_fused2(
    const float4* __restrict__ points4,
    const _Float16* __restrict__ feat_i,
    const float4* __restrict__ op4,
    const int*   __restrict__ nbr_idx,
    const int*   __restrict__ row_start,
    const float* __restrict__ k_points,
    const _Float16* __restrict__ w_t,
    float* __restrict__ out)
{
    __shared__ __align__(16) _Float16 aggT[SEGB * ASTR];        // 31232 B
    __shared__ __align__(16) unsigned char stage[4 * WAVE_LDS]; //  9728 B

    const int tid  = threadIdx.x;
    const int wave = tid >> 6;
    const int lane = tid & 63;
    const int quad = lane >> 4;
    const int l16  = lane & 15;
    const int esl  = lane >> 2;       // edge slot 0..15
    const int kg   = lane & 3;        // kgroup / feat-chunk index
    const int m0   = blockIdx.x * SEGB;

    unsigned char* fbase = stage + wave * WAVE_LDS;
    unsigned char* wbase = fbase + 16 * FSTRIDE;

    // per-lane kernel points (kgroup role)
    float kx[4], ky[4], kz[4];
    #pragma unroll
    for (int t = 0; t < 4; ++t) {
        const int k  = kg * 4 + t;
        const int kk = k < KP ? k : 0;
        kx[t] = k_points[kk * 3 + 0];
        ky[t] = k_points[kk * 3 + 1];
        kz[t] = k_points[kk * 3 + 2];
    }
    const float inv_ext = 1.f / EXTENT;

    // ---- segment bounds for this wave's 8 segments (contiguous edge range)
    int rs[SEGW + 1];
    #pragma unroll
    for (int i = 0; i <= SEGW; ++i) rs[i] = row_start[m0 + wave * SEGW + i];

    // next-nonempty-segment start cascade; sentinel = rs[SEGW] (never consumed)
    int nstart[SEGW];
    nstart[SEGW - 1] = rs[SEGW];
    #pragma unroll
    for (int i = SEGW - 2; i >= 0; --i)
        nstart[i] = (rs[i + 1] < rs[i + 2]) ? rs[i + 1] : nstart[i + 1];
    const int fstart = (rs[0] < rs[1]) ? rs[0] : nstart[0];

    // ---- nbr window + prefetch state ----
    int wb = -0x40000000;     // forces initial window load
    int nbrreg = 0;
    uint4  fc_n = {0, 0, 0, 0};
    float4 p_n  = make_float4(0.f, 0.f, 0.f, 0.f);

    // prefetch gathers for step at uniform edge offset `es`
    auto pref = [&](int es) {
        if (es + 15 > wb + 63) {                 // wave-uniform slide
            wb = es;
            const int a = wb + lane;
            nbrreg = nbr_idx[a < EDG ? a : EDG - 1];
        }
        const int e  = es + esl;                 // <= wb+63 by construction
        const int nb = __shfl(nbrreg, e - wb);
        fc_n = *(const uint4*)(feat_i + nb * FIN + kg * 8);
        p_n  = ((const float4*)points4)[nb];
    };

    pref(fstart);   // first step of first nonempty segment (or dummy)

    // ---- Phase 1: 8 segments, pipelined step stream ----
    #pragma unroll
    for (int j = 0; j < SEGW; ++j) {
        const int e0 = rs[j];
        const int e1 = rs[j + 1];
        const float4 o = op4[m0 + wave * SEGW + j];

        f32x4 c_lo = {0.f, 0.f, 0.f, 0.f};
        f32x4 c_hi = {0.f, 0.f, 0.f, 0.f};

        for (int es = e0; es < e1; es += 16) {
            // take current step's prefetched data, then issue next step's
            const uint4  fc = fc_n;
            const float4 p  = p_n;
            const int nes = (es + 16 < e1) ? es + 16 : nstart[j];
            pref(nes);

            // ---- consume (identical to proven R12 code) ----
            *(uint4*)(fbase + esl * FSTRIDE + kg * 16) = fc;

            const float rx = p.x - o.x, ry = p.y - o.y, rz = p.z - o.z;
            const bool evalid = (es + esl) < e1;
            #pragma unroll
            for (int t = 0; t < 4; ++t) {
                const float dx = rx - kx[t], dy = ry - ky[t], dz = rz - kz[t];
                float w = 1.f - sqrtf(dx * dx + dy * dy + dz * dz) * inv_ext;
                w = w > 0.f ? w : 0.f;
                if (!evalid || (kg * 4 + t) >= KP) w = 0.f;
                *(_Float16*)(wbase + (kg * 4 + t) * WSTRIDE + esl * 2) = (_Float16)w;
            }

            const f16x4 af = *(const f16x4*)(wbase + l16 * WSTRIDE + quad * 8);
            f16x2 w2[4];
            #pragma unroll
            for (int jj = 0; jj < 4; ++jj)
                w2[jj] = *(const f16x2*)(fbase + (quad * 4 + jj) * FSTRIDE + l16 * 4);
            const f16x4 blo = {w2[0][0], w2[1][0], w2[2][0], w2[3][0]};
            const f16x4 bhi = {w2[0][1], w2[1][1], w2[2][1], w2[3][1]};

            c_lo = __builtin_amdgcn_mfma_f32_16x16x16f16(af, blo, c_lo, 0, 0, 0);
            c_hi = __builtin_amdgcn_mfma_f32_16x16x16f16(af, bhi, c_hi, 0, 0, 0);
        }

        // D -> agg tile row (interleaved kf order): byte = k*64 + l16*4
        _Float16* dst = aggT + (wave * SEGW + j) * ASTR;
        #pragma unroll
        for (int r = 0; r < 4; ++r) {
            const int krow = quad * 4 + r;
            if (krow < KP) {
                f16x2 v = {(_Float16)c_lo[r], (_Float16)c_hi[r]};
                *(f16x2*)(dst + krow * 32 + 2 * l16) = v;
            }
        }
    }

    __syncthreads();

    // ---- Phase 2: C[32 segs x 16 cols] per wave = two 16-row tiles ----
    const int bcol = wave * 16 + l16;
    const _Float16* wrow  = w_t + (size_t)bcol * KFDIM + quad * 8;
    const _Float16* arow0 = aggT + l16 * ASTR + quad * 8;
    const _Float16* arow1 = aggT + (16 + l16) * ASTR + quad * 8;

    f32x4 c0 = {0.f, 0.f, 0.f, 0.f};
    f32x4 c1 = {0.f, 0.f, 0.f, 0.f};
    #pragma unroll
    for (int s = 0; s < 15; ++s) {
        const f16x8 b  = *(const f16x8*)(wrow + 32 * s);
        const f16x8 a0 = *(const f16x8*)(arow0 + 32 * s);
        const f16x8 a1 = *(const f16x8*)(arow1 + 32 * s);
        c0 = __builtin_amdgcn_mfma_f32_16x16x32_f16(a0, b, c0, 0, 0, 0);
        c1 = __builtin_amdgcn_mfma_f32_16x16x32_f16(a1, b, c1, 0, 0, 0);
    }

    // C/D: col = lane&15 (-> bcol), row = quad*4 + r (= local segment)
    #pragma unroll
    for (int r = 0; r < 4; ++r) {
        out[(m0 + quad * 4 + r) * COUT + bcol]      = c0[r];
        out[(m0 + 16 + quad * 4 + r) * COUT + bcol] = c1[r];
    }
}

// ============================================================================
// Fallback (small ws, needs 38.4 MB): binary-search K=32 agg + plain gemm.
// ============================================================================
__global__ __launch_bounds__(256, 4) void kpconv_agg_fallback(
    const float* __restrict__ points,
    const float* __restrict__ features,
    const float* __restrict__ output_points,
    const int*   __restrict__ nbr_idx,
    const int*   __restrict__ seg_ids,
    const float* __restrict__ k_points,
    _Float16* __restrict__ agg_g)
{
    __shared__ int seg_start[5];

    const int tid = threadIdx.x;
    const int m0  = blockIdx.x * 4;

    if (tid <= 4) {
        const int target = m0 + tid;
        int lo = 0, hi = EDG;
        while (lo < hi) {
            int mid = (lo + hi) >> 1;
            if (seg_ids[mid] < target) lo = mid + 1; else hi = mid;
        }
        seg_start[tid] = lo;
    }
    __syncthreads();

    const int wave = tid >> 6;
    const int lane = tid & 63;
    const int quad = lane >> 4;
    const int l16  = lane & 15;

    const int m = m0 + wave;
    const float ox = output_points[m * 3 + 0];
    const float oy = output_points[m * 3 + 1];
    const float oz = output_points[m * 3 + 2];

    const int myk = l16 < KP ? l16 : 0;
    const float kpx = k_points[myk * 3 + 0];
    const float kpy = k_points[myk * 3 + 1];
    const float kpz = k_points[myk * 3 + 2];
    const float inv_ext = 1.f / EXTENT;

    const int e0 = seg_start[wave], e1 = seg_start[wave + 1];

    f32x4 c_lo = {0.f, 0.f, 0.f, 0.f};
    f32x4 c_hi = {0.f, 0.f, 0.f, 0.f};

    for (int es = e0; es < e1; es += 32) {
        const int last = e1 - 1;
        const int ebase = es + quad * 8;

        int nb[8];
        #pragma unroll
        for (int j = 0; j < 8; ++j) {
            const int e = ebase + j;
            nb[j] = nbr_idx[e < e1 ? e : last];
        }

        bf16x8 afrag, blo, bhi;
        #pragma unroll
        for (int j = 0; j < 8; ++j) {
            const float* pp = points + nb[j] * 3;
            const float rx = pp[0] - ox;
            const float ry = pp[1] - oy;
            const float rz = pp[2] - oz;
            const float dx = rx - kpx, dy = ry - kpy, dz = rz - kpz;
            const float d2 = dx * dx + dy * dy + dz * dz;
            float w = 1.f - sqrtf(d2) * inv_ext;
            w = w > 0.f ? w : 0.f;
            if (l16 >= KP || ebase + j >= e1) w = 0.f;
            afrag[j] = f2bf(w);
        }

        #pragma unroll
        for (int j = 0; j < 8; ++j) {
            const float* fp = features + nb[j] * FIN + l16;
            blo[j] = f2bf(fp[0]);
            bhi[j] = f2bf(fp[16]);
        }

        c_lo = __builtin_amdgcn_mfma_f32_16x16x32_bf16(afrag, blo, c_lo, 0, 0, 0);
        c_hi = __builtin_amdgcn_mfma_f32_16x16x32_bf16(afrag, bhi, c_hi, 0, 0, 0);
    }

    _Float16* dst = agg_g + (size_t)m * KFDIM;
    #pragma unroll
    for (int r = 0; r < 4; ++r) {
        const int krow = quad * 4 + r;
        if (krow < KP) {
            dst[krow * FIN + l16]      = (_Float16)c_lo[r];
            dst[krow * FIN + 16 + l16] = (_Float16)c_hi[r];
        }
    }
}

__global__ __launch_bounds__(256, 4) void kpconv_gemm_plain(
    const _Float16* __restrict__ agg_g,
    const float* __restrict__ k_values,
    float* __restrict__ out)
{
    const int tid  = threadIdx.x;
    const int wave = tid >> 6;
    const int lane = tid & 63;
    const int quad = lane >> 4;
    const int l16  = lane & 15;
    const int m0   = blockIdx.x * 32;
    const int bcol = wave * 16 + l16;

    f16x8 bfr[15];
    #pragma unroll
    for (int s = 0; s < 15; ++s) {
        #pragma unroll
        for (int j = 0; j < 8; ++j)
            bfr[s][j] = (_Float16)k_values[(32 * s + quad * 8 + j) * COUT + bcol];
    }

    const _Float16* arow0 = agg_g + (size_t)(m0 + l16) * KFDIM + quad * 8;
    const _Float16* arow1 = arow0 + 16 * KFDIM;

    f32x4 c0 = {0.f, 0.f, 0.f, 0.f};
    f32x4 c1 = {0.f, 0.f, 0.f, 0.f};
    #pragma unroll
    for (int s = 0; s < 15; ++s) {
        const f16x8 a0 = *(const f16x8*)(arow0 + 32 * s);
        const f16x8 a1 = *(const f16x8*)(arow1 + 32 * s);
        c0 = __builtin_amdgcn_mfma_f32_16x16x32_f16(a0, bfr[s], c0, 0, 0, 0);
        c1 = __builtin_amdgcn_mfma_f32_16x16x32_f16(a1, bfr[s], c1, 0, 0, 0);
    }

    #pragma unroll
    for (int r = 0; r < 4; ++r) {
        out[(m0 + quad * 4 + r) * COUT + bcol]      = c0[r];
        out[(m0 + 16 + quad * 4 + r) * COUT + bcol] = c1[r];
    }
}

extern "C" void kernel_launch(void* const* d_in, const int* in_sizes, int n_in,
                              void* d_out, int out_size, void* d_ws, size_t ws_size,
                              hipStream_t stream) {
    const float* points        = (const float*)d_in[0];
    const float* features      = (const float*)d_in[1];
    const float* output_points = (const float*)d_in[2];
    const int*   nbr_idx       = (const int*)d_in[3];
    const int*   seg_ids       = (const int*)d_in[4];
    const float* k_points      = (const float*)d_in[5];
    const float* k_values      = (const float*)d_in[6];
    float* out = (float*)d_out;

    const size_t feat_bytes = (size_t)NPTS * FIN * sizeof(_Float16);           // 2.56 MB
    const size_t pts4_bytes = (size_t)NPTS * sizeof(float4);                   // 0.64 MB
    const size_t op4_bytes  = (size_t)MOUT * sizeof(float4);                   // 0.64 MB
    const size_t rs_bytes   = ((size_t)(MOUT + 1) * sizeof(int) + 15) & ~15ul; // 160 KB
    const size_t wt_bytes   = (size_t)KFDIM * COUT * sizeof(_Float16);         // 60 KB
    const size_t full_bytes = feat_bytes + pts4_bytes + op4_bytes + rs_bytes
                            + wt_bytes;                                        // ~4.1 MB

    if (ws_size >= full_bytes) {
        char* p = (char*)d_ws;
        _Float16* feat_i    = (_Float16*)p;  p += feat_bytes;
        float4*   points4   = (float4*)p;    p += pts4_bytes;
        float4*   op4       = (float4*)p;    p += op4_bytes;
        int*      row_start = (int*)p;       p += rs_bytes;
        _Float16* w_t       = (_Float16*)p;

        preprocess_all<<<PRE_BLKS, 256, 0, stream>>>(
            features, feat_i, points, points4, output_points, op4,
            seg_ids, row_start, k_values, w_t);
        kpconv_fused2<<<MOUT / SEGB, 256, 0, stream>>>(
            points4, feat_i, op4, nbr_idx, row_start, k_points, w_t, out);
    } else {
        _Float16* agg_g = (_Float16*)d_ws;   // needs 38.4 MB
        kpconv_agg_fallback<<<MOUT / 4, 256, 0, stream>>>(
            points, features, output_points, nbr_idx, seg_ids, k_points, agg_g);
        kpconv_gemm_plain<<<MOUT / 32, 256, 0, stream>>>(agg_g, k_values, out);
    }
}

// Round 9
// 101.841 us; speedup vs baseline: 1.3293x; 1.0056x over previous
//
#include <hip/hip_runtime.h>

typedef __attribute__((ext_vector_type(8))) short bf16x8;
typedef __attribute__((ext_vector_type(8))) _Float16 f16x8;
typedef __attribute__((ext_vector_type(4))) float f32x4;
typedef __attribute__((ext_vector_type(4))) _Float16 f16x4;
typedef __attribute__((ext_vector_type(2))) _Float16 f16x2;

#define NPTS   40000
#define MOUT   40000
#define EDG    500000
#define FIN    32
#define COUT   64
#define KP     15
#define KFDIM  (KP * FIN)          // 480
#define EXTENT 0.6f

// Phase-1 wave-private staging (R12-proven strides):
#define FSTRIDE 112
#define WSTRIDE 40
#define WAVE_LDS (16 * FSTRIDE + 16 * WSTRIDE)    // 2432 B/wave
// Block agg tile: 16 segments x 488 f16 (976B rows = 61*16B, conflict-free b128)
#define ASTR 488

// R22: preprocess vectorized (G13). feat: 8 f32 -> one uint4 store per lane
// (was 4 scalar f16 stores); row: int4 seg_ids loads (was scalar).
#define FEAT_BLKS  (NPTS * FIN / 8 / 256)         // 625
#define PTS_BLKS   ((NPTS + 255) / 256)           // 157
#define OP_BLKS    ((MOUT + 255) / 256)           // 157
#define ROW_BLKS   ((EDG / 4 + 255) / 256)        // 489
#define WT_BLKS    (KFDIM * COUT / 256)           // 120
#define PRE_BLKS   (FEAT_BLKS + PTS_BLKS + OP_BLKS + ROW_BLKS + WT_BLKS)

__device__ __forceinline__ short f2bf(float x) {
    union { float f; unsigned u; } v; v.f = x;
    unsigned r = (v.u + 0x7fffu + ((v.u >> 16) & 1u)) >> 16;
    return (short)r;
}

// ============================================================================
// Preprocess (ONE launch, branch by block range). R22: vectorized.
//  feat:  feat_i[p][2f'+h] = feat[p][f'+16h]; per lane: 2x float4 load ->
//         pack {A0,B0,A1,B1,A2,B2,A3,B3} -> 1x uint4 store. Casts identical.
//  row:   CSR scatter, 4 edges/lane via int4 load (+1 cached scalar for prev).
//  pts/op/wt: unchanged (small).
// ============================================================================
__global__ __launch_bounds__(256) void preprocess_all(
    const float* __restrict__ features, _Float16* __restrict__ feat_i,
    const float* __restrict__ pts, float4* __restrict__ p4,
    const float* __restrict__ opts, float4* __restrict__ op4,
    const int* __restrict__ seg_ids, int* __restrict__ row_start,
    const float* __restrict__ k_values, _Float16* __restrict__ w_t)
{
    const int bid = blockIdx.x;
    if (bid < FEAT_BLKS) {
        const int u = bid * 256 + threadIdx.x;     // 0..159999 (exact)
        const int p = u >> 2, c = u & 3;
        const float4 A = *(const float4*)(features + p * FIN + c * 4);
        const float4 B = *(const float4*)(features + p * FIN + 16 + c * 4);
        union { f16x2 h[4]; uint4 v; } P;
        P.h[0] = (f16x2){(_Float16)A.x, (_Float16)B.x};
        P.h[1] = (f16x2){(_Float16)A.y, (_Float16)B.y};
        P.h[2] = (f16x2){(_Float16)A.z, (_Float16)B.z};
        P.h[3] = (f16x2){(_Float16)A.w, (_Float16)B.w};
        *(uint4*)(feat_i + p * FIN + c * 8) = P.v;
    } else if (bid < FEAT_BLKS + PTS_BLKS) {
        const int i = (bid - FEAT_BLKS) * 256 + threadIdx.x;
        if (i < NPTS) {
            const float* p = pts + 3 * i;
            p4[i] = make_float4(p[0], p[1], p[2], 0.f);
        }
    } else if (bid < FEAT_BLKS + PTS_BLKS + OP_BLKS) {
        const int i = (bid - FEAT_BLKS - PTS_BLKS) * 256 + threadIdx.x;
        if (i < MOUT) {
            const float* p = opts + 3 * i;
            op4[i] = make_float4(p[0], p[1], p[2], 0.f);
        }
    } else if (bid < FEAT_BLKS + PTS_BLKS + OP_BLKS + ROW_BLKS) {
        const int t4 = (bid - FEAT_BLKS - PTS_BLKS - OP_BLKS) * 256 + threadIdx.x;
        if (t4 < EDG / 4) {                         // EDG % 4 == 0
            const int e0 = t4 * 4;
            const int4 s4 = *(const int4*)(seg_ids + e0);
            int prev = (e0 == 0) ? -1 : seg_ids[e0 - 1];
            #pragma unroll
            for (int j = 0; j < 4; ++j) {
                const int e   = e0 + j;
                const int cur = (j == 0) ? s4.x : (j == 1) ? s4.y
                              : (j == 2) ? s4.z : s4.w;
                for (int m = prev + 1; m <= cur; ++m) row_start[m] = e;
                if (e == EDG - 1)
                    for (int m = cur + 1; m <= MOUT; ++m) row_start[m] = EDG;
                prev = cur;
            }
        }
    } else {
        const int d = (bid - FEAT_BLKS - PTS_BLKS - OP_BLKS - ROW_BLKS) * 256
                      + threadIdx.x;                 // 0 .. 30719
        const int c = d / KFDIM, r = d % KFDIM;
        const int k = r >> 5, q = r & 31;
        const int fp = q >> 1, h = q & 1;
        w_t[d] = (_Float16)k_values[(k * FIN + fp + 16 * h) * COUT + c];
    }
}

// ============================================================================
// Fused kernel — R16 VERBATIM (best measured: 101.9us wall, fused2 ~30us).
// 4 seg/wave, 16 seg/block, 1-step-ahead register prefetch + nbr shfl window.
// R17-R21 established this as the local optimum for phase 1; do not touch.
// ============================================================================
__global__ __launch_bounds__(256, 5) void kpconv_fused2(
    const float4* __restrict__ points4,
    const _Float16* __restrict__ feat_i,
    const float4* __restrict__ op4,
    const int*   __restrict__ nbr_idx,
    const int*   __restrict__ row_start,
    const float* __restrict__ k_points,
    const _Float16* __restrict__ w_t,
    float* __restrict__ out)
{
    __shared__ __align__(16) _Float16 aggT[16 * ASTR];          // 15616 B
    __shared__ __align__(16) unsigned char stage[4 * WAVE_LDS]; //  9728 B

    const int tid  = threadIdx.x;
    const int wave = tid >> 6;
    const int lane = tid & 63;
    const int quad = lane >> 4;
    const int l16  = lane & 15;
    const int esl  = lane >> 2;       // edge slot 0..15
    const int kg   = lane & 3;        // kgroup / feat-chunk index
    const int m0   = blockIdx.x * 16;

    unsigned char* fbase = stage + wave * WAVE_LDS;
    unsigned char* wbase = fbase + 16 * FSTRIDE;

    // per-lane kernel points (kgroup role)
    float kx[4], ky[4], kz[4];
    #pragma unroll
    for (int t = 0; t < 4; ++t) {
        const int k  = kg * 4 + t;
        const int kk = k < KP ? k : 0;
        kx[t] = k_points[kk * 3 + 0];
        ky[t] = k_points[kk * 3 + 1];
        kz[t] = k_points[kk * 3 + 2];
    }
    const float inv_ext = 1.f / EXTENT;

    // ---- segment bounds for this wave's 4 segments (contiguous edge range)
    int rs[5];
    #pragma unroll
    for (int i = 0; i < 5; ++i) rs[i] = row_start[m0 + wave * 4 + i];

    // next-nonempty-segment start cascade; sentinel = rs[4] (never consumed)
    int nstart[4];
    nstart[3] = rs[4];
    nstart[2] = (rs[3] < rs[4]) ? rs[3] : rs[4];
    nstart[1] = (rs[2] < rs[3]) ? rs[2] : nstart[2];
    nstart[0] = (rs[1] < rs[2]) ? rs[1] : nstart[1];
    const int fstart = (rs[0] < rs[1]) ? rs[0] : nstart[0];

    // ---- nbr window + prefetch state ----
    int wb = -0x40000000;     // forces initial window load
    int nbrreg = 0;
    uint4  fc_n = {0, 0, 0, 0};
    float4 p_n  = make_float4(0.f, 0.f, 0.f, 0.f);

    // prefetch gathers for step at uniform edge offset `es`
    auto pref = [&](int es) {
        if (es + 15 > wb + 63) {                 // wave-uniform slide
            wb = es;
            const int a = wb + lane;
            nbrreg = nbr_idx[a < EDG ? a : EDG - 1];
        }
        const int e  = es + esl;                 // <= wb+63 by construction
        const int nb = __shfl(nbrreg, e - wb);
        fc_n = *(const uint4*)(feat_i + nb * FIN + kg * 8);
        p_n  = ((const float4*)points4)[nb];
    };

    pref(fstart);   // first step of first nonempty segment (or dummy)

    // ---- Phase 1: 4 segments, pipelined step stream ----
    #pragma unroll
    for (int j = 0; j < 4; ++j) {
        const int e0 = rs[j];
        const int e1 = rs[j + 1];
        const float4 o = op4[m0 + wave * 4 + j];

        f32x4 c_lo = {0.f, 0.f, 0.f, 0.f};
        f32x4 c_hi = {0.f, 0.f, 0.f, 0.f};

        for (int es = e0; es < e1; es += 16) {
            // take current step's prefetched data, then issue next step's
            const uint4  fc = fc_n;
            const float4 p  = p_n;
            const int nes = (es + 16 < e1) ? es + 16 : nstart[j];
            pref(nes);

            // ---- consume (identical to proven R12 code) ----
            *(uint4*)(fbase + esl * FSTRIDE + kg * 16) = fc;

            const float rx = p.x - o.x, ry = p.y - o.y, rz = p.z - o.z;
            const bool evalid = (es + esl) < e1;
            #pragma unroll
            for (int t = 0; t < 4; ++t) {
                const float dx = rx - kx[t], dy = ry - ky[t], dz = rz - kz[t];
                float w = 1.f - sqrtf(dx * dx + dy * dy + dz * dz) * inv_ext;
                w = w > 0.f ? w : 0.f;
                if (!evalid || (kg * 4 + t) >= KP) w = 0.f;
                *(_Float16*)(wbase + (kg * 4 + t) * WSTRIDE + esl * 2) = (_Float16)w;
            }

            const f16x4 af = *(const f16x4*)(wbase + l16 * WSTRIDE + quad * 8);
            f16x2 w2[4];
            #pragma unroll
            for (int jj = 0; jj < 4; ++jj)
                w2[jj] = *(const f16x2*)(fbase + (quad * 4 + jj) * FSTRIDE + l16 * 4);
            const f16x4 blo = {w2[0][0], w2[1][0], w2[2][0], w2[3][0]};
            const f16x4 bhi = {w2[0][1], w2[1][1], w2[2][1], w2[3][1]};

            c_lo = __builtin_amdgcn_mfma_f32_16x16x16f16(af, blo, c_lo, 0, 0, 0);
            c_hi = __builtin_amdgcn_mfma_f32_16x16x16f16(af, bhi, c_hi, 0, 0, 0);
        }

        // D -> agg tile row (interleaved kf order): byte = k*64 + l16*4
        _Float16* dst = aggT + (wave * 4 + j) * ASTR;
        #pragma unroll
        for (int r = 0; r < 4; ++r) {
            const int krow = quad * 4 + r;
            if (krow < KP) {
                f16x2 v = {(_Float16)c_lo[r], (_Float16)c_hi[r]};
                *(f16x2*)(dst + krow * 32 + 2 * l16) = v;
            }
        }
    }

    __syncthreads();

    // ---- Phase 2: C[16 segs x 16 cols] per wave, B in-loop from w_t ----
    const int bcol = wave * 16 + l16;
    const _Float16* wrow = w_t + (size_t)bcol * KFDIM + quad * 8;
    const _Float16* arow = aggT + l16 * ASTR + quad * 8;

    f32x4 c = {0.f, 0.f, 0.f, 0.f};
    #pragma unroll
    for (int s = 0; s < 15; ++s) {
        const f16x8 a = *(const f16x8*)(arow + 32 * s);
        const f16x8 b = *(const f16x8*)(wrow + 32 * s);
        c = __builtin_amdgcn_mfma_f32_16x16x32_f16(a, b, c, 0, 0, 0);
    }

    // C/D: col = lane&15 (-> bcol), row = quad*4 + r (= local segment)
    #pragma unroll
    for (int r = 0; r < 4; ++r)
        out[(m0 + quad * 4 + r) * COUT + bcol] = c[r];
}

// ============================================================================
// Fallback (small ws, needs 38.4 MB): binary-search K=32 agg + plain gemm.
// ============================================================================
__global__ __launch_bounds__(256, 4) void kpconv_agg_fallback(
    const float* __restrict__ points,
    const float* __restrict__ features,
    const float* __restrict__ output_points,
    const int*   __restrict__ nbr_idx,
    const int*   __restrict__ seg_ids,
    const float* __restrict__ k_points,
    _Float16* __restrict__ agg_g)
{
    __shared__ int seg_start[5];

    const int tid = threadIdx.x;
    const int m0  = blockIdx.x * 4;

    if (tid <= 4) {
        const int target = m0 + tid;
        int lo = 0, hi = EDG;
        while (lo < hi) {
            int mid = (lo + hi) >> 1;
            if (seg_ids[mid] < target) lo = mid + 1; else hi = mid;
        }
        seg_start[tid] = lo;
    }
    __syncthreads();

    const int wave = tid >> 6;
    const int lane = tid & 63;
    const int quad = lane >> 4;
    const int l16  = lane & 15;

    const int m = m0 + wave;
    const float ox = output_points[m * 3 + 0];
    const float oy = output_points[m * 3 + 1];
    const float oz = output_points[m * 3 + 2];

    const int myk = l16 < KP ? l16 : 0;
    const float kpx = k_points[myk * 3 + 0];
    const float kpy = k_points[myk * 3 + 1];
    const float kpz = k_points[myk * 3 + 2];
    const float inv_ext = 1.f / EXTENT;

    const int e0 = seg_start[wave], e1 = seg_start[wave + 1];

    f32x4 c_lo = {0.f, 0.f, 0.f, 0.f};
    f32x4 c_hi = {0.f, 0.f, 0.f, 0.f};

    for (int es = e0; es < e1; es += 32) {
        const int last = e1 - 1;
        const int ebase = es + quad * 8;

        int nb[8];
        #pragma unroll
        for (int j = 0; j < 8; ++j) {
            const int e = ebase + j;
            nb[j] = nbr_idx[e < e1 ? e : last];
        }

        bf16x8 afrag, blo, bhi;
        #pragma unroll
        for (int j = 0; j < 8; ++j) {
            const float* pp = points + nb[j] * 3;
            const float rx = pp[0] - ox;
            const float ry = pp[1] - oy;
            const float rz = pp[2] - oz;
            const float dx = rx - kpx, dy = ry - kpy, dz = rz - kpz;
            const float d2 = dx * dx + dy * dy + dz * dz;
            float w = 1.f - sqrtf(d2) * inv_ext;
            w = w > 0.f ? w : 0.f;
            if (l16 >= KP || ebase + j >= e1) w = 0.f;
            afrag[j] = f2bf(w);
        }

        #pragma unroll
        for (int j = 0; j < 8; ++j) {
            const float* fp = features + nb[j] * FIN + l16;
            blo[j] = f2bf(fp[0]);
            bhi[j] = f2bf(fp[16]);
        }

        c_lo = __builtin_amdgcn_mfma_f32_16x16x32_bf16(afrag, blo, c_lo, 0, 0, 0);
        c_hi = __builtin_amdgcn_mfma_f32_16x16x32_bf16(afrag, bhi, c_hi, 0, 0, 0);
    }

    _Float16* dst = agg_g + (size_t)m * KFDIM;
    #pragma unroll
    for (int r = 0; r < 4; ++r) {
        const int krow = quad * 4 + r;
        if (krow < KP) {
            dst[krow * FIN + l16]      = (_Float16)c_lo[r];
            dst[krow * FIN + 16 + l16] = (_Float16)c_hi[r];
        }
    }
}

__global__ __launch_bounds__(256, 4) void kpconv_gemm_plain(
    const _Float16* __restrict__ agg_g,
    const float* __restrict__ k_values,
    float* __restrict__ out)
{
    const int tid  = threadIdx.x;
    const int wave = tid >> 6;
    const int lane = tid & 63;
    const int quad = lane >> 4;
    const int l16  = lane & 15;
    const int m0   = blockIdx.x * 32;
    const int bcol = wave * 16 + l16;

    f16x8 bfr[15];
    #pragma unroll
    for (int s = 0; s < 15; ++s) {
        #pragma unroll
        for (int j = 0; j < 8; ++j)
            bfr[s][j] = (_Float16)k_values[(32 * s + quad * 8 + j) * COUT + bcol];
    }

    const _Float16* arow0 = agg_g + (size_t)(m0 + l16) * KFDIM + quad * 8;
    const _Float16* arow1 = arow0 + 16 * KFDIM;

    f32x4 c0 = {0.f, 0.f, 0.f, 0.f};
    f32x4 c1 = {0.f, 0.f, 0.f, 0.f};
    #pragma unroll
    for (int s = 0; s < 15; ++s) {
        const f16x8 a0 = *(const f16x8*)(arow0 + 32 * s);
        const f16x8 a1 = *(const f16x8*)(arow1 + 32 * s);
        c0 = __builtin_amdgcn_mfma_f32_16x16x32_f16(a0, bfr[s], c0, 0, 0, 0);
        c1 = __builtin_amdgcn_mfma_f32_16x16x32_f16(a1, bfr[s], c1, 0, 0, 0);
    }

    #pragma unroll
    for (int r = 0; r < 4; ++r) {
        out[(m0 + quad * 4 + r) * COUT + bcol]      = c0[r];
        out[(m0 + 16 + quad * 4 + r) * COUT + bcol] = c1[r];
    }
}

extern "C" void kernel_launch(void* const* d_in, const int* in_sizes, int n_in,
                              void* d_out, int out_size, void* d_ws, size_t ws_size,
                              hipStream_t stream) {
    const float* points        = (const float*)d_in[0];
    const float* features      = (const float*)d_in[1];
    const float* output_points = (const float*)d_in[2];
    const int*   nbr_idx       = (const int*)d_in[3];
    const int*   seg_ids       = (const int*)d_in[4];
    const float* k_points      = (const float*)d_in[5];
    const float* k_values      = (const float*)d_in[6];
    float* out = (float*)d_out;

    const size_t feat_bytes = (size_t)NPTS * FIN * sizeof(_Float16);           // 2.56 MB
    const size_t pts4_bytes = (size_t)NPTS * sizeof(float4);                   // 0.64 MB
    const size_t op4_bytes  = (size_t)MOUT * sizeof(float4);                   // 0.64 MB
    const size_t rs_bytes   = ((size_t)(MOUT + 1) * sizeof(int) + 15) & ~15ul; // 160 KB
    const size_t wt_bytes   = (size_t)KFDIM * COUT * sizeof(_Float16);         // 60 KB
    const size_t full_bytes = feat_bytes + pts4_bytes + op4_bytes + rs_bytes
                            + wt_bytes;                                        // ~4.1 MB

    if (ws_size >= full_bytes) {
        char* p = (char*)d_ws;
        _Float16* feat_i    = (_Float16*)p;  p += feat_bytes;
        float4*   points4   = (float4*)p;    p += pts4_bytes;
        float4*   op4       = (float4*)p;    p += op4_bytes;
        int*      row_start = (int*)p;       p += rs_bytes;
        _Float16* w_t       = (_Float16*)p;

        preprocess_all<<<PRE_BLKS, 256, 0, stream>>>(
            features, feat_i, points, points4, output_points, op4,
            seg_ids, row_start, k_values, w_t);
        kpconv_fused2<<<MOUT / 16, 256, 0, stream>>>(
            points4, feat_i, op4, nbr_idx, row_start, k_points, w_t, out);
    } else {
        _Float16* agg_g = (_Float16*)d_ws;   // needs 38.4 MB
        kpconv_agg_fallback<<<MOUT / 4, 256, 0, stream>>>(
            points, features, output_points, nbr_idx, seg_ids, k_points, agg_g);
        kpconv_gemm_plain<<<MOUT / 32, 256, 0, stream>>>(agg_g, k_values, out);
    }
}